// Round 7
// baseline (36.088 us; speedup 1.0000x reference)
//
#include <hip/hip_runtime.h>
#include <stdint.h>
#include <float.h>

typedef unsigned long long u64;
typedef unsigned int u32;

#define KK 64
#define NN 128
#define NCAND 2081   // 1 + 64 + 2016

__device__ __forceinline__ u64 rdlane64(u64 v, int l) {
    u32 lo = (u32)__builtin_amdgcn_readlane((int)(u32)v, l);
    u32 hi = (u32)__builtin_amdgcn_readlane((int)(u32)(v >> 32), l);
    return ((u64)hi << 32) | lo;
}
__device__ __forceinline__ int ffs128(u64 x0, u64 x1) {
    return x0 ? (__ffsll((long long)x0) - 1) : (x1 ? (63 + __ffsll((long long)x1)) : 0);
}
__device__ __forceinline__ bool bit128(u64 x0, u64 x1, int p) {
    u64 sel = (p < 64) ? x0 : x1;
    return ((sel >> (p & 63)) & 1ull) != 0;
}
// e in [0,2016) -> pair (i,j), 0<=i<j<64, lex order; off(i)=i*(127-i)/2
__device__ __forceinline__ void pair_of(int e, int& i, int& j) {
    float si = sqrtf(4032.25f - 2.0f * (float)e);   // (63.5-i)^2 at boundaries: exact
    i = (int)(63.5f - si);
    i = (i < 0) ? 0 : ((i > 62) ? 62 : i);
    int off = (i * (127 - i)) >> 1;
    if (e < off) { --i; off = (i * (127 - i)) >> 1; }
    else { int off2 = ((i + 1) * (126 - i)) >> 1; if (e >= off2) { ++i; off = off2; } }
    j = e - off + i + 1;
}

// 4 waves per batch item. Wave 0 runs the serial GF(2) pipeline in registers
// (row r in lane r, cross-lane via v_readlane; 4 columns eliminated per
// iteration via SALU speculative forward-substitution). Waves 2-3 stage gm;
// LUT build + candidate search use all 256 threads.
__global__ __launch_bounds__(256, 1) void osd_kernel(
    const float* __restrict__ llr_g,
    const float* __restrict__ gm_g,
    float* __restrict__ out_g)
{
    const int b    = blockIdx.x;
    const int tid  = threadIdx.x;
    const int lane = tid & 63;
    const int wave = tid >> 6;

    __shared__ u64   gorig[2 * KK];      // gm half-rows, original column order
    __shared__ float lrs[NN];            // clipped llr, SORTED (reliability) order
    __shared__ int   idx_sort[NN];       // sorted pos -> original column
    __shared__ int   mrbp[KK];           // parity half of MRB perm: (origcol<<8)|sortedcol
    __shared__ float w[NN];              // |llr| in final (MRB) order
    __shared__ u32   RlA[KK][5];         // gm_mrb rows; stride 5 (coprime 32)
    __shared__ float lut[16][257];       // +1 pad rotates write banks per row
    __shared__ u32   sh_bm[4];           // base mismatch mask
    __shared__ u64   sh_cw[2];           // base codeword
    __shared__ u64   wred[4];            // per-wave packed (S,id)

    // wave-0 registers persisted across barriers
    int pv = 0, oc0 = 0, oc1 = 0, r0 = 0, r1 = 0;
    u64 g0 = 0, g1 = 0;

    // ============ region 0 — parallel across waves ============
    if (wave == 0) {
        float lv0 = llr_g[b * NN + lane];
        float lv1 = llr_g[b * NN + 64 + lane];
        lv0 = fminf(fmaxf(lv0, -100.0f), 100.0f);
        lv1 = fminf(fmaxf(lv1, -100.0f), 100.0f);
        float a0 = fabsf(lv0), a1 = fabsf(lv1);
        #pragma unroll 8
        for (int j = 0; j < 64; ++j) {
            float aj0 = __int_as_float(__builtin_amdgcn_readlane(__float_as_int(a0), j));
            float aj1 = __int_as_float(__builtin_amdgcn_readlane(__float_as_int(a1), j));
            r0 += (aj0 > a0) || (aj0 == a0 && j < lane);   // elem j vs elem lane
            r0 += (aj1 > a0);                               // elem 64+j: idx larger
            r1 += (aj0 > a1) || (aj0 == a1);                // elem j vs 64+lane: idx smaller
            r1 += (aj1 > a1) || (aj1 == a1 && j < lane);
        }
        idx_sort[r0] = lane;        // ranks are distinct: no collisions
        idx_sort[r1] = 64 + lane;
        lrs[r0] = lv0;
        lrs[r1] = lv1;
    } else if (wave >= 2) {
        // waves 2,3: stage gm as bitsets via ballot, all loads in flight
        int h0 = (wave - 2) * 64;
        #pragma unroll 64
        for (int hh = 0; hh < 64; ++hh) {
            int h = h0 + hh;
            float v = gm_g[h * 64 + lane];           // coalesced 256B/instr
            u64 m = __ballot(v != 0.0f);             // bit l = row h>>1, col (h&1)*64+l
            if (lane == 0) gorig[h] = m;
        }
    }
    __syncthreads();   // A: gorig, idx_sort, lrs published

    // ============ region 1 — wave 0 serial pipeline ============
    if (wave == 0) {
        u64 o0 = gorig[2 * lane], o1 = gorig[2 * lane + 1];
        int myoc0 = idx_sort[lane];          // early loads for mrbp packing
        int myoc1 = idx_sort[64 + lane];

        // permute own row to sorted order (register scatter via ranks)
        g0 = 0; g1 = 0;
        #pragma unroll 8
        for (int c = 0; c < 64; ++c) {
            int d0 = __builtin_amdgcn_readlane(r0, c);   // dest of col c (uniform)
            int d1 = __builtin_amdgcn_readlane(r1, c);   // dest of col 64+c
            u64 bb0 = (o0 >> c) & 1ull;
            u64 bb1 = (o1 >> c) & 1ull;
            u64 s0 = bb0 << (d0 & 63);
            u64 s1 = bb1 << (d1 & 63);
            g0 |= (d0 < 64) ? s0 : 0ull;
            g1 |= (d0 < 64) ? 0ull : s0;
            g0 |= (d1 < 64) ? s1 : 0ull;
            g1 |= (d1 < 64) ? 0ull : s1;
        }

        // GF(2) elimination, 4 columns per iteration.
        // Speculative forward-substitution on uniform (SGPR) row values gives
        // pivots pA..pD; per-lane row then applies the 4 conditional XORs in
        // order. Exactly equivalent to 4 serial steps (self-row excluded,
        // zero row -> pivot 0).
        #pragma unroll 4
        for (int t = 0; t < 16; ++t) {
            const int c0 = 4 * t, c1 = c0 + 1, c2 = c0 + 2, c3 = c0 + 3;
            u64 A0 = rdlane64(g0, c0), A1 = rdlane64(g1, c0);
            u64 B0 = rdlane64(g0, c1), B1 = rdlane64(g1, c1);
            u64 C0 = rdlane64(g0, c2), C1 = rdlane64(g1, c2);
            u64 D0 = rdlane64(g0, c3), D1 = rdlane64(g1, c3);
            int pA = ffs128(A0, A1);
            // step c0 on speculative rows
            if (bit128(B0, B1, pA)) { B0 ^= A0; B1 ^= A1; }
            if (bit128(C0, C1, pA)) { C0 ^= A0; C1 ^= A1; }
            if (bit128(D0, D1, pA)) { D0 ^= A0; D1 ^= A1; }
            int pB = ffs128(B0, B1);
            if (bit128(C0, C1, pB)) { C0 ^= B0; C1 ^= B1; }
            if (bit128(D0, D1, pB)) { D0 ^= B0; D1 ^= B1; }
            int pC = ffs128(C0, C1);
            if (bit128(D0, D1, pC)) { D0 ^= C0; D1 ^= C1; }
            int pD = ffs128(D0, D1);
            // apply to per-lane row in order
            bool mA = bit128(g0, g1, pA) && (lane != c0);
            g0 ^= mA ? A0 : 0ull;  g1 ^= mA ? A1 : 0ull;
            bool mB = bit128(g0, g1, pB) && (lane != c1);
            g0 ^= mB ? B0 : 0ull;  g1 ^= mB ? B1 : 0ull;
            bool mC = bit128(g0, g1, pC) && (lane != c2);
            g0 ^= mC ? C0 : 0ull;  g1 ^= mC ? C1 : 0ull;
            bool mD = bit128(g0, g1, pD) && (lane != c3);
            g0 ^= mD ? D0 : 0ull;  g1 ^= mD ? D1 : 0ull;
            pv = (lane == c0) ? pA : (lane == c1) ? pB
               : (lane == c2) ? pC : (lane == c3) ? pD : pv;
        }

        // parity ranks: key = col + 128*count(pivots==col); 64 smallest
        int cnt0 = 0, cnt1 = 0;
        #pragma unroll 8
        for (int m = 0; m < KK; ++m) {
            int pm = __builtin_amdgcn_readlane(pv, m);
            cnt0 += (pm == lane);
            cnt1 += (pm == 64 + lane);
        }
        int k0 = lane + NN * cnt0;
        int k1 = 64 + lane + NN * cnt1;
        int q0 = 0, q1 = 0;
        #pragma unroll 8
        for (int j = 0; j < 64; ++j) {
            int kj0 = __builtin_amdgcn_readlane(k0, j);
            int kj1 = __builtin_amdgcn_readlane(k1, j);
            q0 += (kj0 < k0) + (kj1 < k0);
            q1 += (kj0 < k1) + (kj1 < k1);
        }
        // pack (orig col << 8) | sorted col; keys distinct -> exact 64 slots
        if (q0 < 64) mrbp[q0] = (myoc0 << 8) | lane;
        if (q1 < 64) mrbp[q1] = (myoc1 << 8) | (64 + lane);
        // same-wave LDS ops are in program order: safe to read mrbp below

        // final-order llr + hard decisions
        int mp  = mrbp[lane];
        float f0 = lrs[pv];                  // final pos `lane` = sorted col pv
        float f1 = lrs[mp & 255];            // final pos 64+lane
        oc0 = idx_sort[pv];                  // original cols (used for output)
        oc1 = mp >> 8;
        w[lane]      = fabsf(f0);
        w[64 + lane] = fabsf(f1);
        u64 hb0 = __ballot(f0 < 0.0f);       // hard decisions, final pos 0..63
        u64 hb1 = __ballot(f1 < 0.0f);       // pos 64..127

        // permute eliminated row to MRB order
        u64 R0 = 0, R1 = 0;
        #pragma unroll 8
        for (int ic = 0; ic < 64; ++ic) {    // pivot half via readlane of pv
            int c = __builtin_amdgcn_readlane(pv, ic);
            u64 bit = ((c < 64) ? (g0 >> c) : (g1 >> (c - 64))) & 1ull;
            R0 |= bit << ic;
        }
        #pragma unroll 8
        for (int j = 0; j < 64; ++j) {       // parity half via LDS broadcast
            int c = mrbp[j] & 255;
            u64 bit = ((c < 64) ? (g0 >> c) : (g1 >> (c - 64))) & 1ull;
            R1 |= bit << j;
        }
        RlA[lane][0] = (u32)R0;
        RlA[lane][1] = (u32)(R0 >> 32);
        RlA[lane][2] = (u32)R1;
        RlA[lane][3] = (u32)(R1 >> 32);

        // base codeword = XOR of rows with u_hd==1 (wave butterfly)
        u64 hbit = (hb0 >> lane) & 1ull;
        u64 v0 = hbit ? R0 : 0ull;
        u64 v1 = hbit ? R1 : 0ull;
        #pragma unroll
        for (int off = 32; off; off >>= 1) {
            v0 ^= __shfl_xor(v0, off);
            v1 ^= __shfl_xor(v1, off);
        }
        if (lane == 0) {
            sh_cw[0] = v0; sh_cw[1] = v1;
            u64 bmA = v0 ^ hb0, bmB = v1 ^ hb1;
            sh_bm[0] = (u32)bmA; sh_bm[1] = (u32)(bmA >> 32);
            sh_bm[2] = (u32)bmB; sh_bm[3] = (u32)(bmB >> 32);
        }
    }
    __syncthreads();   // B: w, RlA, sh_bm, sh_cw published

    // ============ region 2 — LUT build, all 256 threads ============
    {
        int p = tid >> 4;                        // table row 0..15
        int t = tid & 15;                        // mask bits 4..7
        const float* wp = &w[p * 8];
        float wv0 = wp[0], wv1 = wp[1], wv2 = wp[2], wv3 = wp[3];
        float wv4 = wp[4], wv5 = wp[5], wv6 = wp[6], wv7 = wp[7];
        float st = ((t & 1) ? wv4 : 0.0f) + ((t & 2) ? wv5 : 0.0f)
                 + ((t & 4) ? wv6 : 0.0f) + ((t & 8) ? wv7 : 0.0f);
        float* lrow = &lut[p][t << 4];
        #pragma unroll
        for (int lo = 0; lo < 16; ++lo)
            lrow[lo] = st + ((lo & 1) ? wv0 : 0.0f) + ((lo & 2) ? wv1 : 0.0f)
                          + ((lo & 4) ? wv2 : 0.0f) + ((lo & 8) ? wv3 : 0.0f);
    }
    __syncthreads();   // C: lut published

    // ============ region 3 — candidate search, all 256 threads ============
    // argmin d == argmax S, S = sum_{mismatched}|llr|. Lexicographic
    // (max S, min id), id order {0=base, 1..64=t1, 65..2080=t2} reproduces the
    // reference's per-round first-argmin + strict-improvement semantics.
    u32 bm0 = sh_bm[0], bm1 = sh_bm[1], bm2 = sh_bm[2], bm3 = sh_bm[3];
    float bestS = -1.0f;                 // every thread sees >=8 real candidates (S>=0)
    int bestId  = 0x7fffffff;
    #pragma unroll
    for (int it = 0; it < 9; ++it) {     // 9 = ceil(2081/256); unroll for load ILP
        int id = tid + it * 256;
        bool valid = id < NCAND;
        int ide = valid ? id : 0;
        u32 x0 = bm0, x1 = bm1, x2 = bm2, x3 = bm3;
        if (ide >= 65) {
            int i, j;
            pair_of(ide - 65, i, j);
            x0 ^= RlA[i][0] ^ RlA[j][0];
            x1 ^= RlA[i][1] ^ RlA[j][1];
            x2 ^= RlA[i][2] ^ RlA[j][2];
            x3 ^= RlA[i][3] ^ RlA[j][3];
        } else if (ide >= 1) {
            int i = ide - 1;
            x0 ^= RlA[i][0]; x1 ^= RlA[i][1]; x2 ^= RlA[i][2]; x3 ^= RlA[i][3];
        }
        float sA = (lut[0][x0 & 255]          + lut[1][(x0 >> 8) & 255])
                 + (lut[2][(x0 >> 16) & 255]  + lut[3][x0 >> 24]);
        float sB = (lut[4][x1 & 255]          + lut[5][(x1 >> 8) & 255])
                 + (lut[6][(x1 >> 16) & 255]  + lut[7][x1 >> 24]);
        float sC = (lut[8][x2 & 255]          + lut[9][(x2 >> 8) & 255])
                 + (lut[10][(x2 >> 16) & 255] + lut[11][x2 >> 24]);
        float sD = (lut[12][x3 & 255]         + lut[13][(x3 >> 8) & 255])
                 + (lut[14][(x3 >> 16) & 255] + lut[15][x3 >> 24]);
        float s = (sA + sB) + (sC + sD);
        if (valid && s > bestS) { bestS = s; bestId = id; }   // ids ascend: min id on tie
    }
    // pack (S, id): S>=0 so float bits are unsigned-monotone; low word favors min id
    u64 key = ((u64)(u32)__float_as_int(bestS) << 32)
            | (u32)(0x7fffffff - bestId);
    #pragma unroll
    for (int off = 32; off; off >>= 1) {
        u64 ok = __shfl_xor(key, off);
        key = (ok > key) ? ok : key;
    }
    if (lane == 0) wred[wave] = key;
    __syncthreads();   // D: per-wave winners published

    // ============ region 4 — final pick + output, wave 0 ============
    if (wave == 0) {
        u64 ka = wred[0], kb = wred[1], kc = wred[2], kd = wred[3];
        u64 km = ka > kb ? ka : kb;
        u64 kn = kc > kd ? kc : kd;
        u64 kk = km > kn ? km : kn;
        int bId = 0x7fffffff - (int)(u32)(kk & 0xffffffffull);
        u64 c0 = sh_cw[0], c1 = sh_cw[1];
        if (bId >= 65) {
            int i, j;
            pair_of(bId - 65, i, j);
            c0 ^= (((u64)RlA[i][1] << 32) | RlA[i][0]) ^ (((u64)RlA[j][1] << 32) | RlA[j][0]);
            c1 ^= (((u64)RlA[i][3] << 32) | RlA[i][2]) ^ (((u64)RlA[j][3] << 32) | RlA[j][2]);
        } else if (bId >= 1) {
            int i = bId - 1;
            c0 ^= ((u64)RlA[i][1] << 32) | RlA[i][0];
            c1 ^= ((u64)RlA[i][3] << 32) | RlA[i][2];
        }
        out_g[b * NN + oc0] = (float)((c0 >> lane) & 1ull);
        out_g[b * NN + oc1] = (float)((c1 >> lane) & 1ull);
    }
}

extern "C" void kernel_launch(void* const* d_in, const int* in_sizes, int n_in,
                              void* d_out, int out_size, void* d_ws, size_t ws_size,
                              hipStream_t stream) {
    const float* llr = (const float*)d_in[0];
    const float* gm  = (const float*)d_in[1];
    float* out       = (float*)d_out;
    int bs = in_sizes[0] / NN;   // 128
    osd_kernel<<<bs, 256, 0, stream>>>(llr, gm, out);
}

// Round 8
// 29.058 us; speedup vs baseline: 1.2419x; 1.2419x over previous
//
#include <hip/hip_runtime.h>
#include <stdint.h>
#include <float.h>

typedef unsigned long long u64;
typedef unsigned int u32;

#define KK 64
#define NN 128
#define NPAIR 2016
#define NCAND 2081   // 1 + 64 + 2016

__device__ __forceinline__ u64 rdlane64(u64 v, int l) {
    u32 lo = (u32)__builtin_amdgcn_readlane((int)(u32)v, l);
    u32 hi = (u32)__builtin_amdgcn_readlane((int)(u32)(v >> 32), l);
    return ((u64)hi << 32) | lo;
}
__device__ __forceinline__ int ffs128(u64 x0, u64 x1) {
    return x0 ? (__ffsll((long long)x0) - 1) : (x1 ? (63 + __ffsll((long long)x1)) : 0);
}
__device__ __forceinline__ bool bit128(u64 x0, u64 x1, int p) {
    u64 sel = (p < 64) ? x0 : x1;
    return ((sel >> (p & 63)) & 1ull) != 0;
}

// 4 waves per batch item. Serial-only work (GF(2) pivot recurrence) stays on
// wave 0 in registers; everything data-parallel (column permutes, parity
// ranking, MRB row permute, LUT, search, output) runs on all 256 threads.
// Each wave handles word-slice `wave` (32 bits) of the 128-bit rows.
__global__ __launch_bounds__(256, 1) void osd_kernel(
    const float* __restrict__ llr_g,
    const float* __restrict__ gm_g,
    float* __restrict__ out_g)
{
    const int b    = blockIdx.x;
    const int tid  = threadIdx.x;
    const int lane = tid & 63;
    const int wave = tid >> 6;

    __shared__ u64   gorig[2 * KK];      // gm half-rows, original column order
    __shared__ float lrs[NN];            // clipped llr, SORTED (reliability) order
    __shared__ int   idx_sort[NN];       // sorted pos -> original column
    __shared__ u32   gS[KK][5];          // rows in sorted col order (stride 5: conflict-free)
    __shared__ int   piv_lds[KK];
    __shared__ int   keys[NN];
    __shared__ int   mrb[NN];            // final pos -> sorted col
    __shared__ int   ocArr[NN];          // final pos -> original col
    __shared__ float w[NN];              // |llr| in final (MRB) order
    __shared__ u32   RlA[KK][5];         // gm_mrb rows (stride 5)
    __shared__ float lut[16][257];       // +1 pad rotates write banks per row
    __shared__ unsigned short pairTab[NPAIR];
    __shared__ u64   sh_hb[2];           // hard decisions, final order
    __shared__ u32   sh_bm[4];           // base mismatch mask
    __shared__ u64   sh_cw[2];           // base codeword
    __shared__ u64   wred[4];            // per-wave packed (S,id)

    // ============ region A — parallel across waves ============
    if (wave == 0) {
        // llr load + clip + stable descending ranks (register-only)
        float lv0 = llr_g[b * NN + lane];
        float lv1 = llr_g[b * NN + 64 + lane];
        lv0 = fminf(fmaxf(lv0, -100.0f), 100.0f);
        lv1 = fminf(fmaxf(lv1, -100.0f), 100.0f);
        float a0 = fabsf(lv0), a1 = fabsf(lv1);
        int r0 = 0, r1 = 0;
        #pragma unroll 8
        for (int j = 0; j < 64; ++j) {
            float aj0 = __int_as_float(__builtin_amdgcn_readlane(__float_as_int(a0), j));
            float aj1 = __int_as_float(__builtin_amdgcn_readlane(__float_as_int(a1), j));
            r0 += (aj0 > a0) || (aj0 == a0 && j < lane);   // elem j vs elem lane
            r0 += (aj1 > a0);                               // elem 64+j: idx larger
            r1 += (aj0 > a1) || (aj0 == a1);                // elem j vs 64+lane: idx smaller
            r1 += (aj1 > a1) || (aj1 == a1 && j < lane);
        }
        idx_sort[r0] = lane;        // ranks distinct: no collisions
        idx_sort[r1] = 64 + lane;
        lrs[r0] = lv0;
        lrs[r1] = lv1;
    } else if (wave == 1) {
        // pair table (static)
        int i = lane;
        int off = 63 * i - (i * (i - 1)) / 2;
        for (int j = i + 1; j < 64; ++j)
            pairTab[off + (j - i - 1)] = (unsigned short)((i << 8) | j);
    } else {
        // waves 2,3: stage gm as bitsets via ballot, all loads in flight
        int h0 = (wave - 2) * 64;
        #pragma unroll 64
        for (int hh = 0; hh < 64; ++hh) {
            int h = h0 + hh;
            float v = gm_g[h * 64 + lane];           // coalesced 256B/instr
            u64 m = __ballot(v != 0.0f);             // bit l = row h>>1, col (h&1)*64+l
            if (lane == 0) gorig[h] = m;
        }
    }
    __syncthreads();   // A: gorig, idx_sort, lrs, pairTab published

    // ============ region B — sorted-order permute, all 256 threads ============
    // thread (wave, lane): builds bits [32*wave, 32*wave+32) of sorted row `lane`
    {
        u64 o0 = gorig[2 * lane], o1 = gorig[2 * lane + 1];
        u32 word = 0;
        const int jbase = 32 * wave;
        #pragma unroll 8
        for (int jj = 0; jj < 32; ++jj) {
            int c = idx_sort[jbase + jj];            // same addr across wave: broadcast
            u32 bit = (u32)(((c < 64) ? (o0 >> c) : (o1 >> (c - 64))) & 1ull);
            word |= bit << jj;
        }
        gS[lane][wave] = word;
    }
    __syncthreads();   // B: gS (sorted rows) published

    // ============ region C — wave 0: GF(2) elimination (serial core) ============
    if (wave == 0) {
        u64 g0 = (u64)gS[lane][0] | ((u64)gS[lane][1] << 32);
        u64 g1 = (u64)gS[lane][2] | ((u64)gS[lane][3] << 32);
        int pv = 0;
        // 4 columns per iteration: speculative forward-substitution on uniform
        // (SGPR) row values gives pivots pA..pD; per-lane row then applies the
        // 4 conditional XORs in order. Exactly equivalent to 4 serial steps.
        #pragma unroll 4
        for (int t = 0; t < 16; ++t) {
            const int c0 = 4 * t, c1 = c0 + 1, c2 = c0 + 2, c3 = c0 + 3;
            u64 A0 = rdlane64(g0, c0), A1 = rdlane64(g1, c0);
            u64 B0 = rdlane64(g0, c1), B1 = rdlane64(g1, c1);
            u64 C0 = rdlane64(g0, c2), C1 = rdlane64(g1, c2);
            u64 D0 = rdlane64(g0, c3), D1 = rdlane64(g1, c3);
            int pA = ffs128(A0, A1);
            if (bit128(B0, B1, pA)) { B0 ^= A0; B1 ^= A1; }
            if (bit128(C0, C1, pA)) { C0 ^= A0; C1 ^= A1; }
            if (bit128(D0, D1, pA)) { D0 ^= A0; D1 ^= A1; }
            int pB = ffs128(B0, B1);
            if (bit128(C0, C1, pB)) { C0 ^= B0; C1 ^= B1; }
            if (bit128(D0, D1, pB)) { D0 ^= B0; D1 ^= B1; }
            int pC = ffs128(C0, C1);
            if (bit128(D0, D1, pC)) { D0 ^= C0; D1 ^= C1; }
            int pD = ffs128(D0, D1);
            bool mA = bit128(g0, g1, pA) && (lane != c0);
            g0 ^= mA ? A0 : 0ull;  g1 ^= mA ? A1 : 0ull;
            bool mB = bit128(g0, g1, pB) && (lane != c1);
            g0 ^= mB ? B0 : 0ull;  g1 ^= mB ? B1 : 0ull;
            bool mC = bit128(g0, g1, pC) && (lane != c2);
            g0 ^= mC ? C0 : 0ull;  g1 ^= mC ? C1 : 0ull;
            bool mD = bit128(g0, g1, pD) && (lane != c3);
            g0 ^= mD ? D0 : 0ull;  g1 ^= mD ? D1 : 0ull;
            pv = (lane == c0) ? pA : (lane == c1) ? pB
               : (lane == c2) ? pC : (lane == c3) ? pD : pv;
        }
        gS[lane][0] = (u32)g0;                 // eliminated rows back to gS
        gS[lane][1] = (u32)(g0 >> 32);
        gS[lane][2] = (u32)g1;
        gS[lane][3] = (u32)(g1 >> 32);
        piv_lds[lane] = pv;
    }
    __syncthreads();   // C: eliminated gS + piv published

    // ============ region D — parity keys, threads 0..127 ============
    if (tid < NN) {
        int cnt = 0;
        #pragma unroll 16
        for (int m = 0; m < KK; ++m)
            cnt += (piv_lds[m] == tid);          // broadcast reads
        keys[tid] = tid + NN * cnt;
    }
    __syncthreads();   // D: keys published

    // ============ region E — rank keys -> MRB permutation, threads 0..127 ============
    if (tid < NN) {
        int k = keys[tid];
        int q = 0;
        #pragma unroll 16
        for (int j = 0; j < NN; ++j)
            q += (keys[j] < k);                  // broadcast reads; keys distinct
        if (tid < KK) mrb[tid] = piv_lds[tid];   // pivot half
        if (q < KK)   mrb[KK + q] = tid;         // parity half: 64 smallest keys
    }
    __syncthreads();   // E: mrb published

    // ============ region F — final-order data + MRB row permute, all threads ============
    if (tid < NN) {
        int sc = mrb[tid];
        float f = lrs[sc];
        w[tid] = fabsf(f);
        ocArr[tid] = idx_sort[sc];
        u64 hbm = __ballot(f < 0.0f);            // waves 0,1 fully active
        if (lane == 0) sh_hb[wave] = hbm;        // wave0: pos 0..63, wave1: 64..127
    }
    {
        // thread (wave, lane): bits [32*wave, 32*wave+32) of MRB row `lane`
        u64 e0 = (u64)gS[lane][0] | ((u64)gS[lane][1] << 32);
        u64 e1 = (u64)gS[lane][2] | ((u64)gS[lane][3] << 32);
        u32 word = 0;
        const int jbase = 32 * wave;
        #pragma unroll 8
        for (int jj = 0; jj < 32; ++jj) {
            int c = mrb[jbase + jj];             // broadcast
            u32 bit = (u32)(((c < 64) ? (e0 >> c) : (e1 >> (c - 64))) & 1ull);
            word |= bit << jj;
        }
        RlA[lane][wave] = word;
    }
    __syncthreads();   // F: w, ocArr, sh_hb, RlA published

    // ============ region G — base codeword (wave 0) + LUT (all threads) ============
    if (wave == 0) {
        u64 hb0 = sh_hb[0];
        u64 R0 = (u64)RlA[lane][0] | ((u64)RlA[lane][1] << 32);
        u64 R1 = (u64)RlA[lane][2] | ((u64)RlA[lane][3] << 32);
        u64 hbit = (hb0 >> lane) & 1ull;
        u64 v0 = hbit ? R0 : 0ull;
        u64 v1 = hbit ? R1 : 0ull;
        #pragma unroll
        for (int off = 32; off; off >>= 1) {
            v0 ^= __shfl_xor(v0, off);
            v1 ^= __shfl_xor(v1, off);
        }
        if (lane == 0) {
            sh_cw[0] = v0; sh_cw[1] = v1;
            u64 bmA = v0 ^ hb0, bmB = v1 ^ sh_hb[1];
            sh_bm[0] = (u32)bmA; sh_bm[1] = (u32)(bmA >> 32);
            sh_bm[2] = (u32)bmB; sh_bm[3] = (u32)(bmB >> 32);
        }
    }
    {
        int p = tid >> 4;                        // table row 0..15
        int t = tid & 15;                        // mask bits 4..7
        const float* wp = &w[p * 8];
        float wv0 = wp[0], wv1 = wp[1], wv2 = wp[2], wv3 = wp[3];
        float wv4 = wp[4], wv5 = wp[5], wv6 = wp[6], wv7 = wp[7];
        float st = ((t & 1) ? wv4 : 0.0f) + ((t & 2) ? wv5 : 0.0f)
                 + ((t & 4) ? wv6 : 0.0f) + ((t & 8) ? wv7 : 0.0f);
        float* lrow = &lut[p][t << 4];
        #pragma unroll
        for (int lo = 0; lo < 16; ++lo)
            lrow[lo] = st + ((lo & 1) ? wv0 : 0.0f) + ((lo & 2) ? wv1 : 0.0f)
                          + ((lo & 4) ? wv2 : 0.0f) + ((lo & 8) ? wv3 : 0.0f);
    }
    __syncthreads();   // G: lut, sh_cw, sh_bm published

    // ============ region H — candidate search, all 256 threads ============
    // argmin d == argmax S, S = sum_{mismatched}|llr|. Lexicographic
    // (max S, min id), id order {0=base, 1..64=t1, 65..2080=t2} reproduces the
    // reference's per-round first-argmin + strict-improvement semantics.
    u32 bm0 = sh_bm[0], bm1 = sh_bm[1], bm2 = sh_bm[2], bm3 = sh_bm[3];
    float bestS = -1.0f;                 // every thread sees >=8 real candidates (S>=0)
    int bestId  = 0x7fffffff;
    #pragma unroll 2
    for (int id = tid; id < NCAND; id += 256) {
        u32 x0 = bm0, x1 = bm1, x2 = bm2, x3 = bm3;
        if (id >= 65) {
            int pr = pairTab[id - 65];
            int i = pr >> 8, j = pr & 255;
            x0 ^= RlA[i][0] ^ RlA[j][0];
            x1 ^= RlA[i][1] ^ RlA[j][1];
            x2 ^= RlA[i][2] ^ RlA[j][2];
            x3 ^= RlA[i][3] ^ RlA[j][3];
        } else if (id >= 1) {
            int i = id - 1;
            x0 ^= RlA[i][0]; x1 ^= RlA[i][1]; x2 ^= RlA[i][2]; x3 ^= RlA[i][3];
        }
        float sA = (lut[0][x0 & 255]          + lut[1][(x0 >> 8) & 255])
                 + (lut[2][(x0 >> 16) & 255]  + lut[3][x0 >> 24]);
        float sB = (lut[4][x1 & 255]          + lut[5][(x1 >> 8) & 255])
                 + (lut[6][(x1 >> 16) & 255]  + lut[7][x1 >> 24]);
        float sC = (lut[8][x2 & 255]          + lut[9][(x2 >> 8) & 255])
                 + (lut[10][(x2 >> 16) & 255] + lut[11][x2 >> 24]);
        float sD = (lut[12][x3 & 255]         + lut[13][(x3 >> 8) & 255])
                 + (lut[14][(x3 >> 16) & 255] + lut[15][x3 >> 24]);
        float s = (sA + sB) + (sC + sD);
        if (s > bestS) { bestS = s; bestId = id; }   // ids ascend: min id on tie
    }
    // pack (S, id): S>=0 so float bits are unsigned-monotone; low word favors min id
    u64 key = ((u64)(u32)__float_as_int(bestS) << 32)
            | (u32)(0x7fffffff - bestId);
    #pragma unroll
    for (int off = 32; off; off >>= 1) {
        u64 ok = __shfl_xor(key, off);
        key = (ok > key) ? ok : key;
    }
    if (lane == 0) wred[wave] = key;
    __syncthreads();   // H: per-wave winners published

    // ============ region I — final pick (redundant) + output, threads 0..127 ============
    if (tid < NN) {
        u64 ka = wred[0], kb = wred[1], kc = wred[2], kd = wred[3];
        u64 km = ka > kb ? ka : kb;
        u64 kn = kc > kd ? kc : kd;
        u64 kk = km > kn ? km : kn;
        int bId = 0x7fffffff - (int)(u32)(kk & 0xffffffffull);
        u64 c0 = sh_cw[0], c1 = sh_cw[1];
        if (bId >= 65) {
            int pr = pairTab[bId - 65];              // uniform: broadcast
            int i = pr >> 8, j = pr & 255;
            c0 ^= (((u64)RlA[i][1] << 32) | RlA[i][0]) ^ (((u64)RlA[j][1] << 32) | RlA[j][0]);
            c1 ^= (((u64)RlA[i][3] << 32) | RlA[i][2]) ^ (((u64)RlA[j][3] << 32) | RlA[j][2]);
        } else if (bId >= 1) {
            int i = bId - 1;
            c0 ^= ((u64)RlA[i][1] << 32) | RlA[i][0];
            c1 ^= ((u64)RlA[i][3] << 32) | RlA[i][2];
        }
        u64 bit = (tid < 64) ? ((c0 >> tid) & 1ull) : ((c1 >> (tid - 64)) & 1ull);
        out_g[b * NN + ocArr[tid]] = (float)bit;
    }
}

extern "C" void kernel_launch(void* const* d_in, const int* in_sizes, int n_in,
                              void* d_out, int out_size, void* d_ws, size_t ws_size,
                              hipStream_t stream) {
    const float* llr = (const float*)d_in[0];
    const float* gm  = (const float*)d_in[1];
    float* out       = (float*)d_out;
    int bs = in_sizes[0] / NN;   // 128
    osd_kernel<<<bs, 256, 0, stream>>>(llr, gm, out);
}

// Round 9
// 28.416 us; speedup vs baseline: 1.2700x; 1.0226x over previous
//
#include <hip/hip_runtime.h>
#include <stdint.h>
#include <float.h>

typedef unsigned long long u64;
typedef unsigned int u32;

#define KK 64
#define NN 128
#define NPAIR 2016
#define NCAND 2081   // 1 + 64 + 2016

__device__ __forceinline__ u64 rdlane64(u64 v, int l) {
    u32 lo = (u32)__builtin_amdgcn_readlane((int)(u32)v, l);
    u32 hi = (u32)__builtin_amdgcn_readlane((int)(u32)(v >> 32), l);
    return ((u64)hi << 32) | lo;
}
__device__ __forceinline__ int ffs128(u64 x0, u64 x1) {
    return x0 ? (__ffsll((long long)x0) - 1) : (x1 ? (63 + __ffsll((long long)x1)) : 0);
}
__device__ __forceinline__ bool bit128(u64 x0, u64 x1, int p) {
    u64 sel = (p < 64) ? x0 : x1;
    return ((sel >> (p & 63)) & 1ull) != 0;
}

// 4 waves per batch item. Serial-only work (GF(2) pivot recurrence + MRB
// selection) stays on wave 0 in registers; everything data-parallel (column
// permutes, MRB row permute, LUT, search, output) runs on all 256 threads.
// Each wave handles word-slice `wave` (32 bits) of the 128-bit rows.
__global__ __launch_bounds__(256, 1) void osd_kernel(
    const float* __restrict__ llr_g,
    const float* __restrict__ gm_g,
    float* __restrict__ out_g)
{
    const int b    = blockIdx.x;
    const int tid  = threadIdx.x;
    const int lane = tid & 63;
    const int wave = tid >> 6;

    __shared__ u32   gOr[KK][5];         // gm rows, original col order (stride 5: conflict-free)
    __shared__ float lrs[NN];            // clipped llr, SORTED (reliability) order
    __shared__ int   idx_sort[NN];       // sorted pos -> original column
    __shared__ u32   gS[KK][5];          // rows in sorted col order (stride 5)
    __shared__ int   mrb[NN];            // final pos -> sorted col
    __shared__ int   ocArr[NN];          // final pos -> original col
    __shared__ float w[NN];              // |llr| in final (MRB) order
    __shared__ u32   RlA[KK][5];         // gm_mrb rows (stride 5)
    __shared__ float lut[16][257];       // +1 pad rotates write banks per row
    __shared__ unsigned short pairTab[NPAIR];
    __shared__ u64   sh_hb[2];           // hard decisions, final order
    __shared__ u32   sh_bm[4];           // base mismatch mask
    __shared__ u64   sh_cw[2];           // base codeword
    __shared__ u64   wred[4];            // per-wave packed (S,id)

    // ============ region A — parallel across waves ============
    if (wave == 0) {
        // llr load + clip + stable descending ranks (register-only)
        float lv0 = llr_g[b * NN + lane];
        float lv1 = llr_g[b * NN + 64 + lane];
        lv0 = fminf(fmaxf(lv0, -100.0f), 100.0f);
        lv1 = fminf(fmaxf(lv1, -100.0f), 100.0f);
        float a0 = fabsf(lv0), a1 = fabsf(lv1);
        int r0 = 0, r1 = 0;
        #pragma unroll 8
        for (int j = 0; j < 64; ++j) {
            float aj0 = __int_as_float(__builtin_amdgcn_readlane(__float_as_int(a0), j));
            float aj1 = __int_as_float(__builtin_amdgcn_readlane(__float_as_int(a1), j));
            r0 += (aj0 > a0) || (aj0 == a0 && j < lane);   // elem j vs elem lane
            r0 += (aj1 > a0);                               // elem 64+j: idx larger
            r1 += (aj0 > a1) || (aj0 == a1);                // elem j vs 64+lane: idx smaller
            r1 += (aj1 > a1) || (aj1 == a1 && j < lane);
        }
        idx_sort[r0] = lane;        // ranks distinct: no collisions
        idx_sort[r1] = 64 + lane;
        lrs[r0] = lv0;
        lrs[r1] = lv1;
    } else if (wave == 1) {
        // pair table (static)
        int i = lane;
        int off = 63 * i - (i * (i - 1)) / 2;
        for (int j = i + 1; j < 64; ++j)
            pairTab[off + (j - i - 1)] = (unsigned short)((i << 8) | j);
    } else {
        // waves 2,3: stage gm as bitsets via ballot, all loads in flight
        int h0 = (wave - 2) * 64;
        #pragma unroll 64
        for (int hh = 0; hh < 64; ++hh) {
            int h = h0 + hh;
            float v = gm_g[h * 64 + lane];           // coalesced 256B/instr
            u64 m = __ballot(v != 0.0f);             // bit l = row h>>1, col (h&1)*64+l
            if (lane == 0) {
                gOr[h >> 1][(h & 1) * 2]     = (u32)m;
                gOr[h >> 1][(h & 1) * 2 + 1] = (u32)(m >> 32);
            }
        }
    }
    __syncthreads();   // A: gOr, idx_sort, lrs, pairTab published

    // ============ region B — sorted-order permute, all 256 threads ============
    // thread (wave, lane): builds bits [32*wave, 32*wave+32) of sorted row `lane`
    {
        u64 o0 = (u64)gOr[lane][0] | ((u64)gOr[lane][1] << 32);   // stride-5: conflict-free
        u64 o1 = (u64)gOr[lane][2] | ((u64)gOr[lane][3] << 32);
        u32 word = 0;
        const int jbase = 32 * wave;
        #pragma unroll 8
        for (int jj = 0; jj < 32; ++jj) {
            int c = idx_sort[jbase + jj];            // same addr across wave: broadcast
            u32 bit = (u32)(((c < 64) ? (o0 >> c) : (o1 >> (c - 64))) & 1ull);
            word |= bit << jj;
        }
        gS[lane][wave] = word;
    }
    __syncthreads();   // B: gS (sorted rows) published

    // ============ region C — wave 0: GF(2) elimination + MRB selection ============
    if (wave == 0) {
        u64 g0 = (u64)gS[lane][0] | ((u64)gS[lane][1] << 32);
        u64 g1 = (u64)gS[lane][2] | ((u64)gS[lane][3] << 32);
        int pv = 0;
        // 4 columns per iteration: speculative forward-substitution on uniform
        // (SGPR) row values gives pivots pA..pD; per-lane row then applies the
        // 4 conditional XORs in order. Exactly equivalent to 4 serial steps.
        #pragma unroll 4
        for (int t = 0; t < 16; ++t) {
            const int c0 = 4 * t, c1 = c0 + 1, c2 = c0 + 2, c3 = c0 + 3;
            u64 A0 = rdlane64(g0, c0), A1 = rdlane64(g1, c0);
            u64 B0 = rdlane64(g0, c1), B1 = rdlane64(g1, c1);
            u64 C0 = rdlane64(g0, c2), C1 = rdlane64(g1, c2);
            u64 D0 = rdlane64(g0, c3), D1 = rdlane64(g1, c3);
            int pA = ffs128(A0, A1);
            if (bit128(B0, B1, pA)) { B0 ^= A0; B1 ^= A1; }
            if (bit128(C0, C1, pA)) { C0 ^= A0; C1 ^= A1; }
            if (bit128(D0, D1, pA)) { D0 ^= A0; D1 ^= A1; }
            int pB = ffs128(B0, B1);
            if (bit128(C0, C1, pB)) { C0 ^= B0; C1 ^= B1; }
            if (bit128(D0, D1, pB)) { D0 ^= B0; D1 ^= B1; }
            int pC = ffs128(C0, C1);
            if (bit128(D0, D1, pC)) { D0 ^= C0; D1 ^= C1; }
            int pD = ffs128(D0, D1);
            bool mA = bit128(g0, g1, pA) && (lane != c0);
            g0 ^= mA ? A0 : 0ull;  g1 ^= mA ? A1 : 0ull;
            bool mB = bit128(g0, g1, pB) && (lane != c1);
            g0 ^= mB ? B0 : 0ull;  g1 ^= mB ? B1 : 0ull;
            bool mC = bit128(g0, g1, pC) && (lane != c2);
            g0 ^= mC ? C0 : 0ull;  g1 ^= mC ? C1 : 0ull;
            bool mD = bit128(g0, g1, pD) && (lane != c3);
            g0 ^= mD ? D0 : 0ull;  g1 ^= mD ? D1 : 0ull;
            pv = (lane == c0) ? pA : (lane == c1) ? pB
               : (lane == c2) ? pC : (lane == c3) ? pD : pv;
        }
        gS[lane][0] = (u32)g0;                 // eliminated rows back to gS
        gS[lane][1] = (u32)(g0 >> 32);
        gS[lane][2] = (u32)g1;
        gS[lane][3] = (u32)(g1 >> 32);

        // MRB permutation, fully in registers.
        // key(col) = col + 128*cnt(col); all cnt>=1 keys (>=128) exceed all
        // cnt==0 keys (<=127), and #nonpivot cols = 128 - #distinct >= 64,
        // so parity half = 64 smallest NON-pivot columns in ascending order.
        u64 m0 = (pv < 64) ? (1ull << pv) : 0ull;
        u64 m1 = (pv >= 64) ? (1ull << (pv - 64)) : 0ull;
        #pragma unroll
        for (int off = 32; off; off >>= 1) {     // OR-butterfly: pivot-hit mask
            m0 |= __shfl_xor(m0, off);
            m1 |= __shfl_xor(m1, off);
        }
        u64 N0 = ~m0, N1 = ~m1;                  // non-pivot column sets
        u64 below = (1ull << lane) - 1;
        int q0 = __popcll(N0 & below);                      // rank of col lane
        int q1 = __popcll(N0) + __popcll(N1 & below);       // rank of col 64+lane
        mrb[lane] = pv;                                     // pivot half
        if (((N0 >> lane) & 1ull) && q0 < 64) mrb[64 + q0] = lane;
        if (((N1 >> lane) & 1ull) && q1 < 64) mrb[64 + q1] = 64 + lane;
    }
    __syncthreads();   // C: eliminated gS + mrb published

    // ============ region F — final-order data + MRB row permute, all threads ============
    if (tid < NN) {
        int sc = mrb[tid];
        float f = lrs[sc];
        w[tid] = fabsf(f);
        ocArr[tid] = idx_sort[sc];
        u64 hbm = __ballot(f < 0.0f);            // waves 0,1 fully active
        if (lane == 0) sh_hb[wave] = hbm;        // wave0: pos 0..63, wave1: 64..127
    }
    {
        // thread (wave, lane): bits [32*wave, 32*wave+32) of MRB row `lane`
        u64 e0 = (u64)gS[lane][0] | ((u64)gS[lane][1] << 32);
        u64 e1 = (u64)gS[lane][2] | ((u64)gS[lane][3] << 32);
        u32 word = 0;
        const int jbase = 32 * wave;
        #pragma unroll 8
        for (int jj = 0; jj < 32; ++jj) {
            int c = mrb[jbase + jj];             // broadcast
            u32 bit = (u32)(((c < 64) ? (e0 >> c) : (e1 >> (c - 64))) & 1ull);
            word |= bit << jj;
        }
        RlA[lane][wave] = word;
    }
    __syncthreads();   // F: w, ocArr, sh_hb, RlA published

    // ============ region G — base codeword (wave 0) + LUT (all threads) ============
    if (wave == 0) {
        u64 hb0 = sh_hb[0];
        u64 R0 = (u64)RlA[lane][0] | ((u64)RlA[lane][1] << 32);
        u64 R1 = (u64)RlA[lane][2] | ((u64)RlA[lane][3] << 32);
        u64 hbit = (hb0 >> lane) & 1ull;
        u64 v0 = hbit ? R0 : 0ull;
        u64 v1 = hbit ? R1 : 0ull;
        #pragma unroll
        for (int off = 32; off; off >>= 1) {
            v0 ^= __shfl_xor(v0, off);
            v1 ^= __shfl_xor(v1, off);
        }
        if (lane == 0) {
            sh_cw[0] = v0; sh_cw[1] = v1;
            u64 bmA = v0 ^ hb0, bmB = v1 ^ sh_hb[1];
            sh_bm[0] = (u32)bmA; sh_bm[1] = (u32)(bmA >> 32);
            sh_bm[2] = (u32)bmB; sh_bm[3] = (u32)(bmB >> 32);
        }
    }
    {
        int p = tid >> 4;                        // table row 0..15
        int t = tid & 15;                        // mask bits 4..7
        const float* wp = &w[p * 8];
        float wv0 = wp[0], wv1 = wp[1], wv2 = wp[2], wv3 = wp[3];
        float wv4 = wp[4], wv5 = wp[5], wv6 = wp[6], wv7 = wp[7];
        float st = ((t & 1) ? wv4 : 0.0f) + ((t & 2) ? wv5 : 0.0f)
                 + ((t & 4) ? wv6 : 0.0f) + ((t & 8) ? wv7 : 0.0f);
        float* lrow = &lut[p][t << 4];
        #pragma unroll
        for (int lo = 0; lo < 16; ++lo)
            lrow[lo] = st + ((lo & 1) ? wv0 : 0.0f) + ((lo & 2) ? wv1 : 0.0f)
                          + ((lo & 4) ? wv2 : 0.0f) + ((lo & 8) ? wv3 : 0.0f);
    }
    __syncthreads();   // G: lut, sh_cw, sh_bm published

    // ============ region H — candidate search, all 256 threads ============
    // argmin d == argmax S, S = sum_{mismatched}|llr|. Lexicographic
    // (max S, min id), id order {0=base, 1..64=t1, 65..2080=t2} reproduces the
    // reference's per-round first-argmin + strict-improvement semantics.
    u32 bm0 = sh_bm[0], bm1 = sh_bm[1], bm2 = sh_bm[2], bm3 = sh_bm[3];
    float bestS = -1.0f;                 // every thread sees >=8 real candidates (S>=0)
    int bestId  = 0x7fffffff;
    #pragma unroll 2
    for (int id = tid; id < NCAND; id += 256) {
        u32 x0 = bm0, x1 = bm1, x2 = bm2, x3 = bm3;
        if (id >= 65) {
            int pr = pairTab[id - 65];
            int i = pr >> 8, j = pr & 255;
            x0 ^= RlA[i][0] ^ RlA[j][0];
            x1 ^= RlA[i][1] ^ RlA[j][1];
            x2 ^= RlA[i][2] ^ RlA[j][2];
            x3 ^= RlA[i][3] ^ RlA[j][3];
        } else if (id >= 1) {
            int i = id - 1;
            x0 ^= RlA[i][0]; x1 ^= RlA[i][1]; x2 ^= RlA[i][2]; x3 ^= RlA[i][3];
        }
        float sA = (lut[0][x0 & 255]          + lut[1][(x0 >> 8) & 255])
                 + (lut[2][(x0 >> 16) & 255]  + lut[3][x0 >> 24]);
        float sB = (lut[4][x1 & 255]          + lut[5][(x1 >> 8) & 255])
                 + (lut[6][(x1 >> 16) & 255]  + lut[7][x1 >> 24]);
        float sC = (lut[8][x2 & 255]          + lut[9][(x2 >> 8) & 255])
                 + (lut[10][(x2 >> 16) & 255] + lut[11][x2 >> 24]);
        float sD = (lut[12][x3 & 255]         + lut[13][(x3 >> 8) & 255])
                 + (lut[14][(x3 >> 16) & 255] + lut[15][x3 >> 24]);
        float s = (sA + sB) + (sC + sD);
        if (s > bestS) { bestS = s; bestId = id; }   // ids ascend: min id on tie
    }
    // pack (S, id): S>=0 so float bits are unsigned-monotone; low word favors min id
    u64 key = ((u64)(u32)__float_as_int(bestS) << 32)
            | (u32)(0x7fffffff - bestId);
    #pragma unroll
    for (int off = 32; off; off >>= 1) {
        u64 ok = __shfl_xor(key, off);
        key = (ok > key) ? ok : key;
    }
    if (lane == 0) wred[wave] = key;
    __syncthreads();   // H: per-wave winners published

    // ============ region I — final pick (redundant) + output, threads 0..127 ============
    if (tid < NN) {
        u64 ka = wred[0], kb = wred[1], kc = wred[2], kd = wred[3];
        u64 km = ka > kb ? ka : kb;
        u64 kn = kc > kd ? kc : kd;
        u64 kk = km > kn ? km : kn;
        int bId = 0x7fffffff - (int)(u32)(kk & 0xffffffffull);
        u64 c0 = sh_cw[0], c1 = sh_cw[1];
        if (bId >= 65) {
            int pr = pairTab[bId - 65];              // uniform: broadcast
            int i = pr >> 8, j = pr & 255;
            c0 ^= (((u64)RlA[i][1] << 32) | RlA[i][0]) ^ (((u64)RlA[j][1] << 32) | RlA[j][0]);
            c1 ^= (((u64)RlA[i][3] << 32) | RlA[i][2]) ^ (((u64)RlA[j][3] << 32) | RlA[j][2]);
        } else if (bId >= 1) {
            int i = bId - 1;
            c0 ^= ((u64)RlA[i][1] << 32) | RlA[i][0];
            c1 ^= ((u64)RlA[i][3] << 32) | RlA[i][2];
        }
        u64 bit = (tid < 64) ? ((c0 >> tid) & 1ull) : ((c1 >> (tid - 64)) & 1ull);
        out_g[b * NN + ocArr[tid]] = (float)bit;
    }
}

extern "C" void kernel_launch(void* const* d_in, const int* in_sizes, int n_in,
                              void* d_out, int out_size, void* d_ws, size_t ws_size,
                              hipStream_t stream) {
    const float* llr = (const float*)d_in[0];
    const float* gm  = (const float*)d_in[1];
    float* out       = (float*)d_out;
    int bs = in_sizes[0] / NN;   // 128
    osd_kernel<<<bs, 256, 0, stream>>>(llr, gm, out);
}

// Round 10
// 23.704 us; speedup vs baseline: 1.5225x; 1.1988x over previous
//
#include <hip/hip_runtime.h>
#include <stdint.h>
#include <float.h>

typedef unsigned long long u64;
typedef unsigned int u32;

#define KK 64
#define NN 128
#define NCAND 2081   // 1 + 64 + 2016

__device__ __forceinline__ u64 rdlane64(u64 v, int l) {
    u32 lo = (u32)__builtin_amdgcn_readlane((int)(u32)v, l);
    u32 hi = (u32)__builtin_amdgcn_readlane((int)(u32)(v >> 32), l);
    return ((u64)hi << 32) | lo;
}
__device__ __forceinline__ int ffs128(u64 x0, u64 x1) {
    return x0 ? (__ffsll((long long)x0) - 1) : (x1 ? (63 + __ffsll((long long)x1)) : 0);
}
__device__ __forceinline__ bool bit128(u64 x0, u64 x1, int p) {
    u64 sel = (p < 64) ? x0 : x1;
    return ((sel >> (p & 63)) & 1ull) != 0;
}
// e in [0,2016) -> pair (i,j), 0<=i<j<64, lex order (validated in R7 run)
__device__ __forceinline__ void pair_of(int e, int& i, int& j) {
    float si = sqrtf(4032.25f - 2.0f * (float)e);
    i = (int)(63.5f - si);
    i = (i < 0) ? 0 : ((i > 62) ? 62 : i);
    int off = (i * (127 - i)) >> 1;
    if (e < off) { --i; off = (i * (127 - i)) >> 1; }
    else { int off2 = ((i + 1) * (126 - i)) >> 1; if (e >= off2) { ++i; off = off2; } }
    j = e - off + i + 1;
}

// 4 waves per batch item. Serial-only work (GF(2) pivot recurrence + MRB
// selection) on wave 0 in registers; staging, ranking, permutes, LUT, search
// and output are split across all 256 threads.
__global__ __launch_bounds__(256, 1) void osd_kernel(
    const float* __restrict__ llr_g,
    const float* __restrict__ gm_g,
    float* __restrict__ out_g)
{
    const int b    = blockIdx.x;
    const int tid  = threadIdx.x;
    const int lane = tid & 63;
    const int wave = tid >> 6;

    __shared__ u32   gOr[KK][5];         // gm rows, original col order (stride 5)
    __shared__ float llr_ch[NN];         // clipped llr, original order
    __shared__ int   prt[NN][5];         // partial ranks (stride 5)
    __shared__ float lrs[NN];            // clipped llr, sorted order
    __shared__ int   idx_sort[NN];       // sorted pos -> original column
    __shared__ u32   gS[KK][5];          // rows, sorted col order (stride 5)
    __shared__ int   mrb[NN];            // final pos -> sorted col
    __shared__ int   ocArr[NN];          // final pos -> original col
    __shared__ float w[NN];              // |llr| in final (MRB) order
    __shared__ u32   RlB[KK][4];         // gm_mrb rows, contiguous (b128 reads)
    __shared__ float lut[16][257];       // +1 pad rotates write banks per row
    __shared__ u64   sh_hb[2];           // hard decisions, final order
    __shared__ u32   sh_bm[4];           // base mismatch mask
    __shared__ u64   sh_cw[2];           // base codeword
    __shared__ u64   wred[4];            // per-wave packed (S,id)

    // ============ region A — staging + partial ranks, all 4 waves ============
    float lv0 = llr_g[b * NN + lane];
    float lv1 = llr_g[b * NN + 64 + lane];
    lv0 = fminf(fmaxf(lv0, -100.0f), 100.0f);
    lv1 = fminf(fmaxf(lv1, -100.0f), 100.0f);
    float a0 = fabsf(lv0), a1 = fabsf(lv1);

    // issue this wave's 32 gm loads up front (latency hidden under rank math)
    float gv[32];
    #pragma unroll
    for (int hh = 0; hh < 32; ++hh)
        gv[hh] = gm_g[(32 * wave + hh) * 64 + lane];

    // partial ranks over comparison-quarter j in [16*wave, 16*wave+16)
    int r0p = 0, r1p = 0;
    {
        const int jb = 16 * wave;        // wave-uniform (SGPR) readlane index
        #pragma unroll
        for (int jj = 0; jj < 16; ++jj) {
            int j = jb + jj;
            float aj0 = __int_as_float(__builtin_amdgcn_readlane(__float_as_int(a0), j));
            float aj1 = __int_as_float(__builtin_amdgcn_readlane(__float_as_int(a1), j));
            r0p += (aj0 > a0) || (aj0 == a0 && j < lane);   // elem j vs elem lane
            r0p += (aj1 > a0);                               // elem 64+j: idx larger
            r1p += (aj0 > a1) || (aj0 == a1);                // elem j vs 64+lane: idx smaller
            r1p += (aj1 > a1) || (aj1 == a1 && j < lane);
        }
    }
    prt[lane][wave]      = r0p;
    prt[64 + lane][wave] = r1p;
    if (wave == 0) {
        llr_ch[lane]      = lv0;
        llr_ch[64 + lane] = lv1;
    }
    // ballots for this wave's gm share
    #pragma unroll
    for (int hh = 0; hh < 32; ++hh) {
        int h = 32 * wave + hh;
        u64 m = __ballot(gv[hh] != 0.0f);            // bit l = row h>>1, col (h&1)*64+l
        if (lane == 0) {
            gOr[h >> 1][(h & 1) * 2]     = (u32)m;
            gOr[h >> 1][(h & 1) * 2 + 1] = (u32)(m >> 32);
        }
    }
    __syncthreads();   // A: gOr, prt, llr_ch published

    // ============ region A2 — combine ranks, threads 0..127 ============
    if (tid < NN) {
        int r = prt[tid][0] + prt[tid][1] + prt[tid][2] + prt[tid][3];
        idx_sort[r] = tid;               // ranks distinct: no collisions
        lrs[r] = llr_ch[tid];
    }
    __syncthreads();   // A2: idx_sort, lrs published

    // ============ region B — sorted-order permute, all 256 threads ============
    // thread (wave, lane): bits [32*wave, 32*wave+32) of sorted row `lane`
    {
        u64 o0 = (u64)gOr[lane][0] | ((u64)gOr[lane][1] << 32);
        u64 o1 = (u64)gOr[lane][2] | ((u64)gOr[lane][3] << 32);
        u32 word = 0;
        const int jbase = 32 * wave;
        #pragma unroll 8
        for (int jj = 0; jj < 32; ++jj) {
            int c = idx_sort[jbase + jj];            // broadcast read
            u32 bit = (u32)(((c < 64) ? (o0 >> c) : (o1 >> (c - 64))) & 1ull);
            word |= bit << jj;
        }
        gS[lane][wave] = word;
    }
    __syncthreads();   // B: gS published

    // ============ region C — wave 0: GF(2) elimination + MRB selection ============
    if (wave == 0) {
        u64 g0 = (u64)gS[lane][0] | ((u64)gS[lane][1] << 32);
        u64 g1 = (u64)gS[lane][2] | ((u64)gS[lane][3] << 32);
        int pv = 0;
        // 4 columns per iteration (speculative forward-substitution on uniform
        // SGPR rows; exactly equivalent to 4 serial steps).
        #pragma unroll 4
        for (int t = 0; t < 16; ++t) {
            const int c0 = 4 * t, c1 = c0 + 1, c2 = c0 + 2, c3 = c0 + 3;
            u64 A0 = rdlane64(g0, c0), A1 = rdlane64(g1, c0);
            u64 B0 = rdlane64(g0, c1), B1 = rdlane64(g1, c1);
            u64 C0 = rdlane64(g0, c2), C1 = rdlane64(g1, c2);
            u64 D0 = rdlane64(g0, c3), D1 = rdlane64(g1, c3);
            int pA = ffs128(A0, A1);
            if (bit128(B0, B1, pA)) { B0 ^= A0; B1 ^= A1; }
            if (bit128(C0, C1, pA)) { C0 ^= A0; C1 ^= A1; }
            if (bit128(D0, D1, pA)) { D0 ^= A0; D1 ^= A1; }
            int pB = ffs128(B0, B1);
            if (bit128(C0, C1, pB)) { C0 ^= B0; C1 ^= B1; }
            if (bit128(D0, D1, pB)) { D0 ^= B0; D1 ^= B1; }
            int pC = ffs128(C0, C1);
            if (bit128(D0, D1, pC)) { D0 ^= C0; D1 ^= C1; }
            int pD = ffs128(D0, D1);
            bool mA = bit128(g0, g1, pA) && (lane != c0);
            g0 ^= mA ? A0 : 0ull;  g1 ^= mA ? A1 : 0ull;
            bool mB = bit128(g0, g1, pB) && (lane != c1);
            g0 ^= mB ? B0 : 0ull;  g1 ^= mB ? B1 : 0ull;
            bool mC = bit128(g0, g1, pC) && (lane != c2);
            g0 ^= mC ? C0 : 0ull;  g1 ^= mC ? C1 : 0ull;
            bool mD = bit128(g0, g1, pD) && (lane != c3);
            g0 ^= mD ? D0 : 0ull;  g1 ^= mD ? D1 : 0ull;
            pv = (lane == c0) ? pA : (lane == c1) ? pB
               : (lane == c2) ? pC : (lane == c3) ? pD : pv;
        }
        gS[lane][0] = (u32)g0;
        gS[lane][1] = (u32)(g0 >> 32);
        gS[lane][2] = (u32)g1;
        gS[lane][3] = (u32)(g1 >> 32);

        // MRB permutation in registers: parity half = 64 smallest non-pivot
        // columns ascending (key = col + 128*cnt ordering collapses to this).
        u64 m0 = (pv < 64) ? (1ull << pv) : 0ull;
        u64 m1 = (pv >= 64) ? (1ull << (pv - 64)) : 0ull;
        #pragma unroll
        for (int off = 32; off; off >>= 1) {
            m0 |= __shfl_xor(m0, off);
            m1 |= __shfl_xor(m1, off);
        }
        u64 N0 = ~m0, N1 = ~m1;
        u64 below = (1ull << lane) - 1;
        int q0 = __popcll(N0 & below);
        int q1 = __popcll(N0) + __popcll(N1 & below);
        mrb[lane] = pv;
        if (((N0 >> lane) & 1ull) && q0 < 64) mrb[64 + q0] = lane;
        if (((N1 >> lane) & 1ull) && q1 < 64) mrb[64 + q1] = 64 + lane;
    }
    __syncthreads();   // C: eliminated gS + mrb published

    // ============ region F — final-order data + MRB row permute ============
    if (tid < NN) {
        int sc = mrb[tid];
        float f = lrs[sc];
        w[tid] = fabsf(f);
        ocArr[tid] = idx_sort[sc];
        u64 hbm = __ballot(f < 0.0f);            // waves 0,1 fully active
        if (lane == 0) sh_hb[wave] = hbm;
    }
    {
        // thread (wave, lane): bits [32*wave, 32*wave+32) of MRB row `lane`
        u64 e0 = (u64)gS[lane][0] | ((u64)gS[lane][1] << 32);
        u64 e1 = (u64)gS[lane][2] | ((u64)gS[lane][3] << 32);
        u32 word = 0;
        const int jbase = 32 * wave;
        #pragma unroll 8
        for (int jj = 0; jj < 32; ++jj) {
            int c = mrb[jbase + jj];             // broadcast
            u32 bit = (u32)(((c < 64) ? (e0 >> c) : (e1 >> (c - 64))) & 1ull);
            word |= bit << jj;
        }
        RlB[lane][wave] = word;                  // contiguous: b128-readable rows
    }
    __syncthreads();   // F: w, ocArr, sh_hb, RlB published

    // ============ region G — base codeword (wave 0) + LUT (all threads) ============
    if (wave == 0) {
        u64 hb0 = sh_hb[0];
        u64 R0 = (u64)RlB[lane][0] | ((u64)RlB[lane][1] << 32);
        u64 R1 = (u64)RlB[lane][2] | ((u64)RlB[lane][3] << 32);
        u64 hbit = (hb0 >> lane) & 1ull;
        u64 v0 = hbit ? R0 : 0ull;
        u64 v1 = hbit ? R1 : 0ull;
        #pragma unroll
        for (int off = 32; off; off >>= 1) {
            v0 ^= __shfl_xor(v0, off);
            v1 ^= __shfl_xor(v1, off);
        }
        if (lane == 0) {
            sh_cw[0] = v0; sh_cw[1] = v1;
            u64 bmA = v0 ^ hb0, bmB = v1 ^ sh_hb[1];
            sh_bm[0] = (u32)bmA; sh_bm[1] = (u32)(bmA >> 32);
            sh_bm[2] = (u32)bmB; sh_bm[3] = (u32)(bmB >> 32);
        }
    }
    {
        int p = tid >> 4;                        // table row 0..15
        int t = tid & 15;                        // mask bits 4..7
        const float* wp = &w[p * 8];
        float wv0 = wp[0], wv1 = wp[1], wv2 = wp[2], wv3 = wp[3];
        float wv4 = wp[4], wv5 = wp[5], wv6 = wp[6], wv7 = wp[7];
        float st = ((t & 1) ? wv4 : 0.0f) + ((t & 2) ? wv5 : 0.0f)
                 + ((t & 4) ? wv6 : 0.0f) + ((t & 8) ? wv7 : 0.0f);
        float* lrow = &lut[p][t << 4];
        #pragma unroll
        for (int lo = 0; lo < 16; ++lo)
            lrow[lo] = st + ((lo & 1) ? wv0 : 0.0f) + ((lo & 2) ? wv1 : 0.0f)
                          + ((lo & 4) ? wv2 : 0.0f) + ((lo & 8) ? wv3 : 0.0f);
    }
    __syncthreads();   // G: lut, sh_cw, sh_bm published

    // ============ region H — candidate search, chunked, all 256 threads ============
    // argmin d == argmax S, S = sum_{mismatched}|llr|. Lexicographic
    // (max S, min id), id order {0=base, 1..64=t1, 65..2080=t2}.
#define SUM16(x0,x1,x2,x3) \
    (((lut[0][(x0) & 255]          + lut[1][((x0) >> 8) & 255])   \
    + (lut[2][((x0) >> 16) & 255]  + lut[3][(x0) >> 24]))         \
    + ((lut[4][(x1) & 255]         + lut[5][((x1) >> 8) & 255])   \
    + (lut[6][((x1) >> 16) & 255]  + lut[7][(x1) >> 24]))         \
    + ((lut[8][(x2) & 255]         + lut[9][((x2) >> 8) & 255])   \
    + (lut[10][((x2) >> 16) & 255] + lut[11][(x2) >> 24]))        \
    + ((lut[12][(x3) & 255]        + lut[13][((x3) >> 8) & 255])  \
    + (lut[14][((x3) >> 16) & 255] + lut[15][(x3) >> 24])))

    u32 bm0 = sh_bm[0], bm1 = sh_bm[1], bm2 = sh_bm[2], bm3 = sh_bm[3];
    float bestS = -1.0f;
    int bestId  = 0x7fffffff;
    // part 1: ids 0..64 on threads 0..64
    if (tid <= 64) {
        u32 x0 = bm0, x1 = bm1, x2 = bm2, x3 = bm3;
        if (tid >= 1) {
            const u32* rp = &RlB[tid - 1][0];
            x0 ^= rp[0]; x1 ^= rp[1]; x2 ^= rp[2]; x3 ^= rp[3];
        }
        bestS = SUM16(x0, x1, x2, x3);
        bestId = tid;
    }
    // part 2: contiguous chunk of the t2 region (7-8 candidates/thread);
    // row_i hoisted per i-run, row_j one b128 per candidate.
    {
        int e    = (tid * 2016) >> 8;
        int eEnd = ((tid + 1) * 2016) >> 8;
        int i, j;
        pair_of(e, i, j);
        const u32* rp = &RlB[i][0];
        u32 bi0 = bm0 ^ rp[0], bi1 = bm1 ^ rp[1], bi2 = bm2 ^ rp[2], bi3 = bm3 ^ rp[3];
        while (e < eEnd) {
            const u32* rj = &RlB[j][0];
            u32 x0 = bi0 ^ rj[0], x1 = bi1 ^ rj[1], x2 = bi2 ^ rj[2], x3 = bi3 ^ rj[3];
            float s = SUM16(x0, x1, x2, x3);
            int id = 65 + e;
            if (s > bestS || (s == bestS && id < bestId)) { bestS = s; bestId = id; }
            ++e; ++j;
            if (j == 64) {
                ++i; j = i + 1;
                const u32* rn = &RlB[i][0];
                bi0 = bm0 ^ rn[0]; bi1 = bm1 ^ rn[1]; bi2 = bm2 ^ rn[2]; bi3 = bm3 ^ rn[3];
            }
        }
    }
    // pack (S, id): S>=0 so float bits are unsigned-monotone; low word favors min id
    u64 key = ((u64)(u32)__float_as_int(bestS) << 32)
            | (u32)(0x7fffffff - bestId);
    #pragma unroll
    for (int off = 32; off; off >>= 1) {
        u64 ok = __shfl_xor(key, off);
        key = (ok > key) ? ok : key;
    }
    if (lane == 0) wred[wave] = key;
    __syncthreads();   // H: per-wave winners published

    // ============ region I — final pick (redundant) + output, threads 0..127 ============
    if (tid < NN) {
        u64 ka = wred[0], kb = wred[1], kc = wred[2], kd = wred[3];
        u64 km = ka > kb ? ka : kb;
        u64 kn = kc > kd ? kc : kd;
        u64 kk = km > kn ? km : kn;
        int bId = 0x7fffffff - (int)(u32)(kk & 0xffffffffull);
        u64 c0 = sh_cw[0], c1 = sh_cw[1];
        if (bId >= 65) {
            int i, j;
            pair_of(bId - 65, i, j);                 // uniform
            c0 ^= ((u64)RlB[i][0] | ((u64)RlB[i][1] << 32))
                ^ ((u64)RlB[j][0] | ((u64)RlB[j][1] << 32));
            c1 ^= ((u64)RlB[i][2] | ((u64)RlB[i][3] << 32))
                ^ ((u64)RlB[j][2] | ((u64)RlB[j][3] << 32));
        } else if (bId >= 1) {
            int i = bId - 1;
            c0 ^= (u64)RlB[i][0] | ((u64)RlB[i][1] << 32);
            c1 ^= (u64)RlB[i][2] | ((u64)RlB[i][3] << 32);
        }
        u64 bit = (tid < 64) ? ((c0 >> tid) & 1ull) : ((c1 >> (tid - 64)) & 1ull);
        out_g[b * NN + ocArr[tid]] = (float)bit;
    }
#undef SUM16
}

extern "C" void kernel_launch(void* const* d_in, const int* in_sizes, int n_in,
                              void* d_out, int out_size, void* d_ws, size_t ws_size,
                              hipStream_t stream) {
    const float* llr = (const float*)d_in[0];
    const float* gm  = (const float*)d_in[1];
    float* out       = (float*)d_out;
    int bs = in_sizes[0] / NN;   // 128
    osd_kernel<<<bs, 256, 0, stream>>>(llr, gm, out);
}

// Round 11
// 21.834 us; speedup vs baseline: 1.6528x; 1.0856x over previous
//
#include <hip/hip_runtime.h>
#include <stdint.h>
#include <float.h>

typedef unsigned long long u64;
typedef unsigned int u32;

#define KK 64
#define NN 128
#define NCAND 2081   // 1 + 64 + 2016

__device__ __forceinline__ u64 rdlane64(u64 v, int l) {
    u32 lo = (u32)__builtin_amdgcn_readlane((int)(u32)v, l);
    u32 hi = (u32)__builtin_amdgcn_readlane((int)(u32)(v >> 32), l);
    return ((u64)hi << 32) | lo;
}
__device__ __forceinline__ int ffs128(u64 x0, u64 x1) {
    return x0 ? (__ffsll((long long)x0) - 1) : (x1 ? (63 + __ffsll((long long)x1)) : 0);
}
__device__ __forceinline__ bool bit128(u64 x0, u64 x1, int p) {
    u64 sel = (p < 64) ? x0 : x1;
    return ((sel >> (p & 63)) & 1ull) != 0;
}
// e in [0,2016) -> pair (i,j), 0<=i<j<64, lex order (validated in R7/R10 runs)
__device__ __forceinline__ void pair_of(int e, int& i, int& j) {
    float si = sqrtf(4032.25f - 2.0f * (float)e);
    i = (int)(63.5f - si);
    i = (i < 0) ? 0 : ((i > 62) ? 62 : i);
    int off = (i * (127 - i)) >> 1;
    if (e < off) { --i; off = (i * (127 - i)) >> 1; }
    else { int off2 = ((i + 1) * (126 - i)) >> 1; if (e >= off2) { ++i; off = off2; } }
    j = e - off + i + 1;
}

// 4 waves per batch item. Everything runs in SORTED column space (the MRB
// column permutation is score-invariant and only matters for u_hd, which we
// get from the pivot indices directly). Wave 0: serial GF(2) elimination +
// base codeword; waves 1-3 build the LUT concurrently (in C's shadow).
__global__ __launch_bounds__(256, 1) void osd_kernel(
    const float* __restrict__ llr_g,
    const float* __restrict__ gm_g,
    float* __restrict__ out_g)
{
    const int b    = blockIdx.x;
    const int tid  = threadIdx.x;
    const int lane = tid & 63;
    const int wave = tid >> 6;

    __shared__ u32   gOr[KK][5];         // gm rows, original col order (stride 5)
    __shared__ float llr_ch[NN];         // clipped llr, original order
    __shared__ int   prt[NN][5];         // partial ranks (stride 5)
    __shared__ float lrs[NN];            // clipped llr, sorted order
    __shared__ int   idx_sort[NN];       // sorted pos -> original column
    __shared__ u32   gS[KK][5];          // rows, sorted col order (stride 5)
    __shared__ __align__(16) u32 RlB[KK][4];  // eliminated rows (contiguous, b128)
    __shared__ float lut[16][257];       // byte-subset sums of |lrs| (+1 pad)
    __shared__ u32   sh_bm[4];           // base mismatch mask (sorted space)
    __shared__ u64   sh_cw[2];           // base codeword (sorted space)
    __shared__ u64   wred[4];            // per-wave packed (S,id)

    // ============ region A — staging + partial ranks, all 4 waves ============
    float lv0 = llr_g[b * NN + lane];
    float lv1 = llr_g[b * NN + 64 + lane];
    lv0 = fminf(fmaxf(lv0, -100.0f), 100.0f);
    lv1 = fminf(fmaxf(lv1, -100.0f), 100.0f);
    float a0 = fabsf(lv0), a1 = fabsf(lv1);

    // issue this wave's 32 gm loads up front (latency hidden under rank math)
    float gv[32];
    #pragma unroll
    for (int hh = 0; hh < 32; ++hh)
        gv[hh] = gm_g[(32 * wave + hh) * 64 + lane];

    // partial ranks over comparison-quarter j in [16*wave, 16*wave+16)
    int r0p = 0, r1p = 0;
    {
        const int jb = 16 * wave;        // wave-uniform (SGPR) readlane index
        #pragma unroll
        for (int jj = 0; jj < 16; ++jj) {
            int j = jb + jj;
            float aj0 = __int_as_float(__builtin_amdgcn_readlane(__float_as_int(a0), j));
            float aj1 = __int_as_float(__builtin_amdgcn_readlane(__float_as_int(a1), j));
            r0p += (aj0 > a0) || (aj0 == a0 && j < lane);   // elem j vs elem lane
            r0p += (aj1 > a0);                               // elem 64+j: idx larger
            r1p += (aj0 > a1) || (aj0 == a1);                // elem j vs 64+lane: idx smaller
            r1p += (aj1 > a1) || (aj1 == a1 && j < lane);
        }
    }
    prt[lane][wave]      = r0p;
    prt[64 + lane][wave] = r1p;
    if (wave == 0) {
        llr_ch[lane]      = lv0;
        llr_ch[64 + lane] = lv1;
    }
    // ballots for this wave's gm share
    #pragma unroll
    for (int hh = 0; hh < 32; ++hh) {
        int h = 32 * wave + hh;
        u64 m = __ballot(gv[hh] != 0.0f);            // bit l = row h>>1, col (h&1)*64+l
        if (lane == 0) {
            gOr[h >> 1][(h & 1) * 2]     = (u32)m;
            gOr[h >> 1][(h & 1) * 2 + 1] = (u32)(m >> 32);
        }
    }
    __syncthreads();   // A: gOr, prt, llr_ch published

    // ============ region A2 — combine ranks, threads 0..127 ============
    if (tid < NN) {
        int r = prt[tid][0] + prt[tid][1] + prt[tid][2] + prt[tid][3];
        idx_sort[r] = tid;               // ranks distinct: no collisions
        lrs[r] = llr_ch[tid];
    }
    __syncthreads();   // A2: idx_sort, lrs published

    // ============ region B — sorted-order permute, all 256 threads ============
    // thread (wave, lane): bits [32*wave, 32*wave+32) of sorted row `lane`
    {
        u64 o0 = (u64)gOr[lane][0] | ((u64)gOr[lane][1] << 32);
        u64 o1 = (u64)gOr[lane][2] | ((u64)gOr[lane][3] << 32);
        u32 word = 0;
        const int jbase = 32 * wave;
        #pragma unroll 8
        for (int jj = 0; jj < 32; ++jj) {
            int c = idx_sort[jbase + jj];            // broadcast read
            u32 bit = (u32)(((c < 64) ? (o0 >> c) : (o1 >> (c - 64))) & 1ull);
            word |= bit << jj;
        }
        gS[lane][wave] = word;
    }
    __syncthreads();   // B: gS published

    // ============ region C — wave 0: elimination + base codeword;
    // ============             waves 1-3: LUT build (runs in C's shadow) ============
    if (wave == 0) {
        u64 g0 = (u64)gS[lane][0] | ((u64)gS[lane][1] << 32);
        u64 g1 = (u64)gS[lane][2] | ((u64)gS[lane][3] << 32);
        int pv = 0;
        // 4 columns per iteration (speculative forward-substitution on uniform
        // SGPR rows; exactly equivalent to 4 serial steps).
        #pragma unroll 4
        for (int t = 0; t < 16; ++t) {
            const int c0 = 4 * t, c1 = c0 + 1, c2 = c0 + 2, c3 = c0 + 3;
            u64 A0 = rdlane64(g0, c0), A1 = rdlane64(g1, c0);
            u64 B0 = rdlane64(g0, c1), B1 = rdlane64(g1, c1);
            u64 C0 = rdlane64(g0, c2), C1 = rdlane64(g1, c2);
            u64 D0 = rdlane64(g0, c3), D1 = rdlane64(g1, c3);
            int pA = ffs128(A0, A1);
            if (bit128(B0, B1, pA)) { B0 ^= A0; B1 ^= A1; }
            if (bit128(C0, C1, pA)) { C0 ^= A0; C1 ^= A1; }
            if (bit128(D0, D1, pA)) { D0 ^= A0; D1 ^= A1; }
            int pB = ffs128(B0, B1);
            if (bit128(C0, C1, pB)) { C0 ^= B0; C1 ^= B1; }
            if (bit128(D0, D1, pB)) { D0 ^= B0; D1 ^= B1; }
            int pC = ffs128(C0, C1);
            if (bit128(D0, D1, pC)) { D0 ^= C0; D1 ^= C1; }
            int pD = ffs128(D0, D1);
            bool mA = bit128(g0, g1, pA) && (lane != c0);
            g0 ^= mA ? A0 : 0ull;  g1 ^= mA ? A1 : 0ull;
            bool mB = bit128(g0, g1, pB) && (lane != c1);
            g0 ^= mB ? B0 : 0ull;  g1 ^= mB ? B1 : 0ull;
            bool mC = bit128(g0, g1, pC) && (lane != c2);
            g0 ^= mC ? C0 : 0ull;  g1 ^= mC ? C1 : 0ull;
            bool mD = bit128(g0, g1, pD) && (lane != c3);
            g0 ^= mD ? D0 : 0ull;  g1 ^= mD ? D1 : 0ull;
            pv = (lane == c0) ? pA : (lane == c1) ? pB
               : (lane == c2) ? pC : (lane == c3) ? pD : pv;
        }
        // eliminated rows -> contiguous RlB (search reads them as b128)
        RlB[lane][0] = (u32)g0;
        RlB[lane][1] = (u32)(g0 >> 32);
        RlB[lane][2] = (u32)g1;
        RlB[lane][3] = (u32)(g1 >> 32);

        // hard decisions in sorted space + base codeword
        float s0 = lrs[lane], s1 = lrs[64 + lane];
        u64 hd0 = __ballot(s0 < 0.0f);           // bit l = hd at sorted col l
        u64 hd1 = __ballot(s1 < 0.0f);           // bit l = hd at sorted col 64+l
        u64 hbit = bit128(hd0, hd1, pv) ? 1ull : 0ull;   // u_hd[lane]
        u64 v0 = hbit ? g0 : 0ull;
        u64 v1 = hbit ? g1 : 0ull;
        #pragma unroll
        for (int off = 32; off; off >>= 1) {
            v0 ^= __shfl_xor(v0, off);
            v1 ^= __shfl_xor(v1, off);
        }
        if (lane == 0) {
            sh_cw[0] = v0; sh_cw[1] = v1;
            u64 bmA = v0 ^ hd0, bmB = v1 ^ hd1;
            sh_bm[0] = (u32)bmA; sh_bm[1] = (u32)(bmA >> 32);
            sh_bm[2] = (u32)bmB; sh_bm[3] = (u32)(bmB >> 32);
        }
    } else {
        // waves 1-3 (192 threads): byte-subset-sum LUT over |lrs| (sorted order).
        // 256 (p,t) cells; thread u does cell u and (u<64: cell u+192).
        int u = tid - 64;
        #pragma unroll 2
        for (int cell = u; cell < 256; cell += 192) {
            int p = cell >> 4;                   // table row 0..15
            int t = cell & 15;                   // mask bits 4..7
            const float* wp = &lrs[p * 8];
            float wv0 = fabsf(wp[0]), wv1 = fabsf(wp[1]);
            float wv2 = fabsf(wp[2]), wv3 = fabsf(wp[3]);
            float wv4 = fabsf(wp[4]), wv5 = fabsf(wp[5]);
            float wv6 = fabsf(wp[6]), wv7 = fabsf(wp[7]);
            float st = ((t & 1) ? wv4 : 0.0f) + ((t & 2) ? wv5 : 0.0f)
                     + ((t & 4) ? wv6 : 0.0f) + ((t & 8) ? wv7 : 0.0f);
            float* lrow = &lut[p][t << 4];
            #pragma unroll
            for (int lo = 0; lo < 16; ++lo)
                lrow[lo] = st + ((lo & 1) ? wv0 : 0.0f) + ((lo & 2) ? wv1 : 0.0f)
                              + ((lo & 4) ? wv2 : 0.0f) + ((lo & 8) ? wv3 : 0.0f);
        }
    }
    __syncthreads();   // C: RlB, sh_cw, sh_bm, lut published

    // ============ region H — candidate search, chunked, all 256 threads ============
    // argmin d == argmax S, S = sum_{mismatched}|llr| (column-order invariant,
    // computed in sorted space). Lexicographic (max S, min id), id order
    // {0=base, 1..64=t1 by row, 65..2080=t2 pairs lex}.
#define SUM16(x0,x1,x2,x3) \
    (((lut[0][(x0) & 255]          + lut[1][((x0) >> 8) & 255])   \
    + (lut[2][((x0) >> 16) & 255]  + lut[3][(x0) >> 24]))         \
    + ((lut[4][(x1) & 255]         + lut[5][((x1) >> 8) & 255])   \
    + (lut[6][((x1) >> 16) & 255]  + lut[7][(x1) >> 24]))         \
    + ((lut[8][(x2) & 255]         + lut[9][((x2) >> 8) & 255])   \
    + (lut[10][((x2) >> 16) & 255] + lut[11][(x2) >> 24]))        \
    + ((lut[12][(x3) & 255]        + lut[13][((x3) >> 8) & 255])  \
    + (lut[14][((x3) >> 16) & 255] + lut[15][(x3) >> 24])))

    u32 bm0 = sh_bm[0], bm1 = sh_bm[1], bm2 = sh_bm[2], bm3 = sh_bm[3];
    float bestS = -1.0f;
    int bestId  = 0x7fffffff;
    // part 1: ids 0..64 on threads 0..64
    if (tid <= 64) {
        u32 x0 = bm0, x1 = bm1, x2 = bm2, x3 = bm3;
        if (tid >= 1) {
            const u32* rp = &RlB[tid - 1][0];
            x0 ^= rp[0]; x1 ^= rp[1]; x2 ^= rp[2]; x3 ^= rp[3];
        }
        bestS = SUM16(x0, x1, x2, x3);
        bestId = tid;
    }
    // part 2: contiguous chunk of the t2 region (7-8 candidates/thread);
    // row_i hoisted per i-run, row_j one b128 per candidate.
    {
        int e    = (tid * 2016) >> 8;
        int eEnd = ((tid + 1) * 2016) >> 8;
        int i, j;
        pair_of(e, i, j);
        const u32* rp = &RlB[i][0];
        u32 bi0 = bm0 ^ rp[0], bi1 = bm1 ^ rp[1], bi2 = bm2 ^ rp[2], bi3 = bm3 ^ rp[3];
        while (e < eEnd) {
            const u32* rj = &RlB[j][0];
            u32 x0 = bi0 ^ rj[0], x1 = bi1 ^ rj[1], x2 = bi2 ^ rj[2], x3 = bi3 ^ rj[3];
            float s = SUM16(x0, x1, x2, x3);
            int id = 65 + e;
            if (s > bestS || (s == bestS && id < bestId)) { bestS = s; bestId = id; }
            ++e; ++j;
            if (j == 64) {
                ++i; j = i + 1;
                const u32* rn = &RlB[i][0];
                bi0 = bm0 ^ rn[0]; bi1 = bm1 ^ rn[1]; bi2 = bm2 ^ rn[2]; bi3 = bm3 ^ rn[3];
            }
        }
    }
    // pack (S, id): S>=0 so float bits are unsigned-monotone; low word favors min id
    u64 key = ((u64)(u32)__float_as_int(bestS) << 32)
            | (u32)(0x7fffffff - bestId);
    #pragma unroll
    for (int off = 32; off; off >>= 1) {
        u64 ok = __shfl_xor(key, off);
        key = (ok > key) ? ok : key;
    }
    if (lane == 0) wred[wave] = key;
    __syncthreads();   // H: per-wave winners published

    // ============ region I — final pick (redundant) + output, threads 0..127 ============
    if (tid < NN) {
        u64 ka = wred[0], kb = wred[1], kc = wred[2], kd = wred[3];
        u64 km = ka > kb ? ka : kb;
        u64 kn = kc > kd ? kc : kd;
        u64 kk = km > kn ? km : kn;
        int bId = 0x7fffffff - (int)(u32)(kk & 0xffffffffull);
        u64 c0 = sh_cw[0], c1 = sh_cw[1];
        if (bId >= 65) {
            int i, j;
            pair_of(bId - 65, i, j);                 // uniform
            c0 ^= ((u64)RlB[i][0] | ((u64)RlB[i][1] << 32))
                ^ ((u64)RlB[j][0] | ((u64)RlB[j][1] << 32));
            c1 ^= ((u64)RlB[i][2] | ((u64)RlB[i][3] << 32))
                ^ ((u64)RlB[j][2] | ((u64)RlB[j][3] << 32));
        } else if (bId >= 1) {
            int i = bId - 1;
            c0 ^= (u64)RlB[i][0] | ((u64)RlB[i][1] << 32);
            c1 ^= (u64)RlB[i][2] | ((u64)RlB[i][3] << 32);
        }
        // bit at sorted col `tid` -> original column idx_sort[tid]
        u64 bit = (tid < 64) ? ((c0 >> tid) & 1ull) : ((c1 >> (tid - 64)) & 1ull);
        out_g[b * NN + idx_sort[tid]] = (float)bit;
    }
#undef SUM16
}

extern "C" void kernel_launch(void* const* d_in, const int* in_sizes, int n_in,
                              void* d_out, int out_size, void* d_ws, size_t ws_size,
                              hipStream_t stream) {
    const float* llr = (const float*)d_in[0];
    const float* gm  = (const float*)d_in[1];
    float* out       = (float*)d_out;
    int bs = in_sizes[0] / NN;   // 128
    osd_kernel<<<bs, 256, 0, stream>>>(llr, gm, out);
}

// Round 12
// 21.486 us; speedup vs baseline: 1.6796x; 1.0162x over previous
//
#include <hip/hip_runtime.h>
#include <stdint.h>
#include <float.h>

typedef unsigned long long u64;
typedef unsigned int u32;

#define KK 64
#define NN 128
#define NPAIR 2016
#define NCAND 2081   // 1 + 64 + 2016

__device__ __forceinline__ u64 rdlane64(u64 v, int l) {
    u32 lo = (u32)__builtin_amdgcn_readlane((int)(u32)v, l);
    u32 hi = (u32)__builtin_amdgcn_readlane((int)(u32)(v >> 32), l);
    return ((u64)hi << 32) | lo;
}
__device__ __forceinline__ int ffs128(u64 x0, u64 x1) {
    return x0 ? (__ffsll((long long)x0) - 1) : (x1 ? (63 + __ffsll((long long)x1)) : 0);
}
__device__ __forceinline__ bool bit128(u64 x0, u64 x1, int p) {
    u64 sel = (p < 64) ? x0 : x1;
    return ((sel >> (p & 63)) & 1ull) != 0;
}

// 4 waves per batch item. Everything runs in SORTED column space (the MRB
// column permutation is score-invariant; u_hd comes from pivot indices).
// Wave 0: serial GF(2) elimination + base codeword; waves 1-3 build the LUT
// in its shadow. Search: 8 branch-free strided candidates per thread.
__global__ __launch_bounds__(256, 1) void osd_kernel(
    const float* __restrict__ llr_g,
    const float* __restrict__ gm_g,
    float* __restrict__ out_g)
{
    const int b    = blockIdx.x;
    const int tid  = threadIdx.x;
    const int lane = tid & 63;
    const int wave = tid >> 6;

    __shared__ u32   gOr[KK][5];         // gm rows, original col order (stride 5)
    __shared__ float llr_ch[NN];         // clipped llr, original order
    __shared__ int   prt[NN][5];         // partial ranks (stride 5)
    __shared__ float lrs[NN];            // clipped llr, sorted order
    __shared__ int   idx_sort[NN];       // sorted pos -> original column
    __shared__ u32   gS[KK][5];          // rows, sorted col order (stride 5)
    __shared__ __align__(16) u32 RlB[KK][4];  // eliminated rows (contiguous, b128)
    __shared__ float lut[16][257];       // byte-subset sums of |lrs| (+1 pad)
    __shared__ unsigned short pairTab[NPAIR];  // (i<<8)|j, lex order
    __shared__ u32   sh_bm[4];           // base mismatch mask (sorted space)
    __shared__ u64   sh_cw[2];           // base codeword (sorted space)
    __shared__ u64   wred[4];            // per-wave packed (S,id)

    // ============ region A — staging + partial ranks, all 4 waves ============
    float lv0 = llr_g[b * NN + lane];
    float lv1 = llr_g[b * NN + 64 + lane];
    lv0 = fminf(fmaxf(lv0, -100.0f), 100.0f);
    lv1 = fminf(fmaxf(lv1, -100.0f), 100.0f);
    float a0 = fabsf(lv0), a1 = fabsf(lv1);

    // issue this wave's 32 gm loads up front (latency hidden under rank math)
    float gv[32];
    #pragma unroll
    for (int hh = 0; hh < 32; ++hh)
        gv[hh] = gm_g[(32 * wave + hh) * 64 + lane];

    // partial ranks over comparison-quarter j in [16*wave, 16*wave+16)
    int r0p = 0, r1p = 0;
    {
        const int jb = 16 * wave;        // wave-uniform (SGPR) readlane index
        #pragma unroll
        for (int jj = 0; jj < 16; ++jj) {
            int j = jb + jj;
            float aj0 = __int_as_float(__builtin_amdgcn_readlane(__float_as_int(a0), j));
            float aj1 = __int_as_float(__builtin_amdgcn_readlane(__float_as_int(a1), j));
            r0p += (aj0 > a0) || (aj0 == a0 && j < lane);   // elem j vs elem lane
            r0p += (aj1 > a0);                               // elem 64+j: idx larger
            r1p += (aj0 > a1) || (aj0 == a1);                // elem j vs 64+lane: idx smaller
            r1p += (aj1 > a1) || (aj1 == a1 && j < lane);
        }
    }
    prt[lane][wave]      = r0p;
    prt[64 + lane][wave] = r1p;
    if (wave == 0) {
        llr_ch[lane]      = lv0;
        llr_ch[64 + lane] = lv1;
    } else if (wave == 1) {
        // pair table (static), built in the HBM-latency shadow, off wave 0
        int i = lane;
        int off = 63 * i - (i * (i - 1)) / 2;
        for (int j = i + 1; j < 64; ++j)
            pairTab[off + (j - i - 1)] = (unsigned short)((i << 8) | j);
    }
    // ballots for this wave's gm share
    #pragma unroll
    for (int hh = 0; hh < 32; ++hh) {
        int h = 32 * wave + hh;
        u64 m = __ballot(gv[hh] != 0.0f);            // bit l = row h>>1, col (h&1)*64+l
        if (lane == 0) {
            gOr[h >> 1][(h & 1) * 2]     = (u32)m;
            gOr[h >> 1][(h & 1) * 2 + 1] = (u32)(m >> 32);
        }
    }
    __syncthreads();   // A: gOr, prt, llr_ch, pairTab published

    // ============ region A2 — combine ranks, threads 0..127 ============
    if (tid < NN) {
        int r = prt[tid][0] + prt[tid][1] + prt[tid][2] + prt[tid][3];
        idx_sort[r] = tid;               // ranks distinct: no collisions
        lrs[r] = llr_ch[tid];
    }
    __syncthreads();   // A2: idx_sort, lrs published

    // ============ region B — sorted-order permute, all 256 threads ============
    // thread (wave, lane): bits [32*wave, 32*wave+32) of sorted row `lane`
    {
        u64 o0 = (u64)gOr[lane][0] | ((u64)gOr[lane][1] << 32);
        u64 o1 = (u64)gOr[lane][2] | ((u64)gOr[lane][3] << 32);
        u32 word = 0;
        const int jbase = 32 * wave;
        #pragma unroll 8
        for (int jj = 0; jj < 32; ++jj) {
            int c = idx_sort[jbase + jj];            // broadcast read
            u32 bit = (u32)(((c < 64) ? (o0 >> c) : (o1 >> (c - 64))) & 1ull);
            word |= bit << jj;
        }
        gS[lane][wave] = word;
    }
    __syncthreads();   // B: gS published

    // ============ region C — wave 0: elimination + base codeword;
    // ============             waves 1-3: LUT build (runs in C's shadow) ============
    if (wave == 0) {
        u64 g0 = (u64)gS[lane][0] | ((u64)gS[lane][1] << 32);
        u64 g1 = (u64)gS[lane][2] | ((u64)gS[lane][3] << 32);
        int pv = 0;
        // 4 columns per iteration (speculative forward-substitution on uniform
        // SGPR rows; exactly equivalent to 4 serial steps).
        #pragma unroll 4
        for (int t = 0; t < 16; ++t) {
            const int c0 = 4 * t, c1 = c0 + 1, c2 = c0 + 2, c3 = c0 + 3;
            u64 A0 = rdlane64(g0, c0), A1 = rdlane64(g1, c0);
            u64 B0 = rdlane64(g0, c1), B1 = rdlane64(g1, c1);
            u64 C0 = rdlane64(g0, c2), C1 = rdlane64(g1, c2);
            u64 D0 = rdlane64(g0, c3), D1 = rdlane64(g1, c3);
            int pA = ffs128(A0, A1);
            if (bit128(B0, B1, pA)) { B0 ^= A0; B1 ^= A1; }
            if (bit128(C0, C1, pA)) { C0 ^= A0; C1 ^= A1; }
            if (bit128(D0, D1, pA)) { D0 ^= A0; D1 ^= A1; }
            int pB = ffs128(B0, B1);
            if (bit128(C0, C1, pB)) { C0 ^= B0; C1 ^= B1; }
            if (bit128(D0, D1, pB)) { D0 ^= B0; D1 ^= B1; }
            int pC = ffs128(C0, C1);
            if (bit128(D0, D1, pC)) { D0 ^= C0; D1 ^= C1; }
            int pD = ffs128(D0, D1);
            bool mA = bit128(g0, g1, pA) && (lane != c0);
            g0 ^= mA ? A0 : 0ull;  g1 ^= mA ? A1 : 0ull;
            bool mB = bit128(g0, g1, pB) && (lane != c1);
            g0 ^= mB ? B0 : 0ull;  g1 ^= mB ? B1 : 0ull;
            bool mC = bit128(g0, g1, pC) && (lane != c2);
            g0 ^= mC ? C0 : 0ull;  g1 ^= mC ? C1 : 0ull;
            bool mD = bit128(g0, g1, pD) && (lane != c3);
            g0 ^= mD ? D0 : 0ull;  g1 ^= mD ? D1 : 0ull;
            pv = (lane == c0) ? pA : (lane == c1) ? pB
               : (lane == c2) ? pC : (lane == c3) ? pD : pv;
        }
        // eliminated rows -> contiguous RlB (search reads them as b128)
        RlB[lane][0] = (u32)g0;
        RlB[lane][1] = (u32)(g0 >> 32);
        RlB[lane][2] = (u32)g1;
        RlB[lane][3] = (u32)(g1 >> 32);

        // hard decisions in sorted space + base codeword
        float s0 = lrs[lane], s1 = lrs[64 + lane];
        u64 hd0 = __ballot(s0 < 0.0f);           // bit l = hd at sorted col l
        u64 hd1 = __ballot(s1 < 0.0f);           // bit l = hd at sorted col 64+l
        u64 hbit = bit128(hd0, hd1, pv) ? 1ull : 0ull;   // u_hd[lane]
        u64 v0 = hbit ? g0 : 0ull;
        u64 v1 = hbit ? g1 : 0ull;
        #pragma unroll
        for (int off = 32; off; off >>= 1) {
            v0 ^= __shfl_xor(v0, off);
            v1 ^= __shfl_xor(v1, off);
        }
        if (lane == 0) {
            sh_cw[0] = v0; sh_cw[1] = v1;
            u64 bmA = v0 ^ hd0, bmB = v1 ^ hd1;
            sh_bm[0] = (u32)bmA; sh_bm[1] = (u32)(bmA >> 32);
            sh_bm[2] = (u32)bmB; sh_bm[3] = (u32)(bmB >> 32);
        }
    } else {
        // waves 1-3 (192 threads): byte-subset-sum LUT over |lrs| (sorted order).
        int u = tid - 64;
        #pragma unroll 2
        for (int cell = u; cell < 256; cell += 192) {
            int p = cell >> 4;                   // table row 0..15
            int t = cell & 15;                   // mask bits 4..7
            const float* wp = &lrs[p * 8];
            float wv0 = fabsf(wp[0]), wv1 = fabsf(wp[1]);
            float wv2 = fabsf(wp[2]), wv3 = fabsf(wp[3]);
            float wv4 = fabsf(wp[4]), wv5 = fabsf(wp[5]);
            float wv6 = fabsf(wp[6]), wv7 = fabsf(wp[7]);
            float st = ((t & 1) ? wv4 : 0.0f) + ((t & 2) ? wv5 : 0.0f)
                     + ((t & 4) ? wv6 : 0.0f) + ((t & 8) ? wv7 : 0.0f);
            float* lrow = &lut[p][t << 4];
            #pragma unroll
            for (int lo = 0; lo < 16; ++lo)
                lrow[lo] = st + ((lo & 1) ? wv0 : 0.0f) + ((lo & 2) ? wv1 : 0.0f)
                              + ((lo & 4) ? wv2 : 0.0f) + ((lo & 8) ? wv3 : 0.0f);
        }
    }
    __syncthreads();   // C: RlB, sh_cw, sh_bm, lut published

    // ============ region H — candidate search, branch-free strided ============
    // argmin d == argmax S, S = sum_{mismatched}|llr| (column-order invariant).
    // Lexicographic (max S, min id), id order {0=base, 1..64=t1, 65..2080=t2}.
#define SUM16(x0,x1,x2,x3) \
    (((lut[0][(x0) & 255]          + lut[1][((x0) >> 8) & 255])   \
    + (lut[2][((x0) >> 16) & 255]  + lut[3][(x0) >> 24]))         \
    + ((lut[4][(x1) & 255]         + lut[5][((x1) >> 8) & 255])   \
    + (lut[6][((x1) >> 16) & 255]  + lut[7][(x1) >> 24]))         \
    + ((lut[8][(x2) & 255]         + lut[9][((x2) >> 8) & 255])   \
    + (lut[10][((x2) >> 16) & 255] + lut[11][(x2) >> 24]))        \
    + ((lut[12][(x3) & 255]        + lut[13][((x3) >> 8) & 255])  \
    + (lut[14][((x3) >> 16) & 255] + lut[15][(x3) >> 24])))

    u32 bm0 = sh_bm[0], bm1 = sh_bm[1], bm2 = sh_bm[2], bm3 = sh_bm[3];
    float bestS = -1.0f;
    int bestId  = 0x7fffffff;
    // part 1: ids 0..64 on threads 0..64
    if (tid <= 64) {
        u32 x0 = bm0, x1 = bm1, x2 = bm2, x3 = bm3;
        if (tid >= 1) {
            const uint4 r = *reinterpret_cast<const uint4*>(&RlB[tid - 1][0]);
            x0 ^= r.x; x1 ^= r.y; x2 ^= r.z; x3 ^= r.w;
        }
        bestS = SUM16(x0, x1, x2, x3);
        bestId = tid;
    }
    // part 2: 8 strided, fully independent candidates per thread (ILP).
    #pragma unroll
    for (int it = 0; it < 8; ++it) {
        int e = tid + it * 256;                  // covers [0,2016) exactly once
        bool valid = e < NPAIR;
        int ee = valid ? e : 0;
        int pr = pairTab[ee];
        int i = pr >> 8, j = pr & 255;
        const uint4 ri = *reinterpret_cast<const uint4*>(&RlB[i][0]);
        const uint4 rj = *reinterpret_cast<const uint4*>(&RlB[j][0]);
        u32 x0 = bm0 ^ ri.x ^ rj.x;
        u32 x1 = bm1 ^ ri.y ^ rj.y;
        u32 x2 = bm2 ^ ri.z ^ rj.z;
        u32 x3 = bm3 ^ ri.w ^ rj.w;
        float s = SUM16(x0, x1, x2, x3);
        // per-thread ids ascend across iterations: '>' keeps earliest on ties
        if (valid && s > bestS) { bestS = s; bestId = 65 + e; }
    }
    // pack (S, id): S>=0 so float bits are unsigned-monotone; low word favors min id
    u64 key = ((u64)(u32)__float_as_int(bestS) << 32)
            | (u32)(0x7fffffff - bestId);
    #pragma unroll
    for (int off = 32; off; off >>= 1) {
        u64 ok = __shfl_xor(key, off);
        key = (ok > key) ? ok : key;
    }
    if (lane == 0) wred[wave] = key;
    __syncthreads();   // H: per-wave winners published

    // ============ region I — final pick (redundant) + output, threads 0..127 ============
    if (tid < NN) {
        u64 ka = wred[0], kb = wred[1], kc = wred[2], kd = wred[3];
        u64 km = ka > kb ? ka : kb;
        u64 kn = kc > kd ? kc : kd;
        u64 kk = km > kn ? km : kn;
        int bId = 0x7fffffff - (int)(u32)(kk & 0xffffffffull);
        u64 c0 = sh_cw[0], c1 = sh_cw[1];
        if (bId >= 65) {
            int pr = pairTab[bId - 65];              // uniform broadcast read
            int i = pr >> 8, j = pr & 255;
            c0 ^= ((u64)RlB[i][0] | ((u64)RlB[i][1] << 32))
                ^ ((u64)RlB[j][0] | ((u64)RlB[j][1] << 32));
            c1 ^= ((u64)RlB[i][2] | ((u64)RlB[i][3] << 32))
                ^ ((u64)RlB[j][2] | ((u64)RlB[j][3] << 32));
        } else if (bId >= 1) {
            int i = bId - 1;
            c0 ^= (u64)RlB[i][0] | ((u64)RlB[i][1] << 32);
            c1 ^= (u64)RlB[i][2] | ((u64)RlB[i][3] << 32);
        }
        // bit at sorted col `tid` -> original column idx_sort[tid]
        u64 bit = (tid < 64) ? ((c0 >> tid) & 1ull) : ((c1 >> (tid - 64)) & 1ull);
        out_g[b * NN + idx_sort[tid]] = (float)bit;
    }
#undef SUM16
}

extern "C" void kernel_launch(void* const* d_in, const int* in_sizes, int n_in,
                              void* d_out, int out_size, void* d_ws, size_t ws_size,
                              hipStream_t stream) {
    const float* llr = (const float*)d_in[0];
    const float* gm  = (const float*)d_in[1];
    float* out       = (float*)d_out;
    int bs = in_sizes[0] / NN;   // 128
    osd_kernel<<<bs, 256, 0, stream>>>(llr, gm, out);
}